// Round 10
// baseline (444.304 us; speedup 1.0000x reference)
//
#include <hip/hip_runtime.h>
#include <hip/hip_bf16.h>

constexpr int F_IN  = 512;
constexpr int HID   = 16;
constexpr int NCLS  = 40;
constexpr int CHUNK = 4096;   // edges per chunk
constexpr int BMAX  = 800;    // max buckets (N=100000 -> NB=782)
constexpr int SMAX  = 6144;   // max edges per bucket
constexpr int GT    = 64;     // gemm1c nodes per block

// ---- zero the scan pad [lo,hi) of counts ----
__global__ void k_zpad(int* __restrict__ counts, int lo, int hi) {
  int i = lo + blockIdx.x * 256 + threadIdx.x;
  if (i < hi) counts[i] = 0;
}

// ---- Pass A: per-chunk histogram of dst buckets (LDS atomics only) ----
__global__ void k_count(const int* __restrict__ dst, int* __restrict__ counts,
                        int E, int NB, int NBLK) {
  __shared__ int hist[BMAX];
  int t = threadIdx.x;
  for (int b = t; b < BMAX; b += 256) hist[b] = 0;
  __syncthreads();
  int base = blockIdx.x * CHUNK;
  for (int i = 0; i < CHUNK; i += 256) {
    int e = base + i + t;
    if (e < E) atomicAdd(&hist[dst[e] >> 7], 1);
  }
  __syncthreads();
  for (int b = t; b < NB; b += 256) counts[b * NBLK + blockIdx.x] = hist[b];
}

// ---- scan over counts (bucket-major), 3 stages, in-place ----
__global__ void k_scanA(const int* __restrict__ a, int* __restrict__ bsum) {
  __shared__ int sd[256];
  int t = threadIdx.x;
  int4 v = reinterpret_cast<const int4*>(a)[blockIdx.x * 256 + t];
  sd[t] = v.x + v.y + v.z + v.w;
  __syncthreads();
  for (int off = 128; off > 0; off >>= 1) {
    if (t < off) sd[t] += sd[t + off];
    __syncthreads();
  }
  if (!t) bsum[blockIdx.x] = sd[0];
}

__global__ void k_scanB(int* __restrict__ bsum, int nb) {
  __shared__ int sd[1024];
  int t = threadIdx.x;
  int v = (t < nb) ? bsum[t] : 0;
  sd[t] = v;
  __syncthreads();
  for (int off = 1; off < 1024; off <<= 1) {
    int add = (t >= off) ? sd[t - off] : 0;
    __syncthreads();
    sd[t] += add;
    __syncthreads();
  }
  if (t < nb) bsum[t] = sd[t] - v;  // exclusive
}

__global__ void k_scanC(int* __restrict__ a, const int* __restrict__ bsum) {
  __shared__ int sd[256];
  int t = threadIdx.x;
  int4 v = reinterpret_cast<int4*>(a)[blockIdx.x * 256 + t];
  int ts = v.x + v.y + v.z + v.w;
  sd[t] = ts;
  __syncthreads();
  for (int off = 1; off < 256; off <<= 1) {
    int add = (t >= off) ? sd[t - off] : 0;
    __syncthreads();
    sd[t] += add;
    __syncthreads();
  }
  int pre = bsum[blockIdx.x] + sd[t] - ts;
  int4 w;
  w.x = pre; w.y = pre + v.x; w.z = w.y + v.y; w.w = w.z + v.z;
  reinterpret_cast<int4*>(a)[blockIdx.x * 256 + t] = w;
}

// ---- Pass B: chunk-local LDS counting sort by bucket; STREAMING writes ----
__global__ void __launch_bounds__(256)
k_scat2(const int* __restrict__ src, const int* __restrict__ dst,
        const float* __restrict__ ew, uint2* __restrict__ payloadA,
        int* __restrict__ segs, int E, int NB) {
  __shared__ uint2 ebuf[CHUNK];
  __shared__ int hist[1024];
  __shared__ int sc[256];
  int t = threadIdx.x;
  int c = blockIdx.x;
  int cbase = c * CHUNK;
  int sz = min(CHUNK, E - cbase);
#pragma unroll
  for (int i = 0; i < 4; ++i) hist[t + 256 * i] = 0;
  __syncthreads();
  uint2 pk[16];
  int key[16];
#pragma unroll
  for (int r = 0; r < 16; ++r) {
    int i = r * 256 + t;
    int e = cbase + i;
    if (i < sz) {
      int s = src[e], d = dst[e];
      pk[r] = make_uint2(((unsigned)s << 7) | (unsigned)(d & 127),
                         __float_as_uint(ew[e]));
      key[r] = d >> 7;
      atomicAdd(&hist[key[r]], 1);
    } else {
      key[r] = -1;
    }
  }
  __syncthreads();
  int h0 = hist[4 * t], h1 = hist[4 * t + 1], h2 = hist[4 * t + 2], h3 = hist[4 * t + 3];
  int tsum = h0 + h1 + h2 + h3;
  sc[t] = tsum;
  __syncthreads();
  for (int off = 1; off < 256; off <<= 1) {
    int add = (t >= off) ? sc[t - off] : 0;
    __syncthreads();
    sc[t] += add;
    __syncthreads();
  }
  int pre = sc[t] - tsum;
  __syncthreads();
  hist[4 * t]     = pre;
  hist[4 * t + 1] = pre + h0;
  hist[4 * t + 2] = pre + h0 + h1;
  hist[4 * t + 3] = pre + h0 + h1 + h2;
  __syncthreads();
  size_t sb = (size_t)c * (NB + 1);
  for (int b = t; b < NB; b += 256) segs[sb + b] = hist[b];
  if (t == 0) segs[sb + NB] = sz;
  __syncthreads();
#pragma unroll
  for (int r = 0; r < 16; ++r) {
    if (key[r] >= 0) {
      int pos = atomicAdd(&hist[key[r]], 1);
      ebuf[pos] = pk[r];
    }
  }
  __syncthreads();
  for (int i = t; i < sz; i += 256) payloadA[cbase + i] = ebuf[i];
}

// ---- Pass C: per-bucket assembly + node counting sort; streaming writes ----
__global__ void __launch_bounds__(256)
k_sortb2(const uint2* __restrict__ payloadA, const int* __restrict__ segs,
         const int* __restrict__ cnts, uint2* __restrict__ payloadB,
         int* __restrict__ rs, float* __restrict__ dis,
         int N, int NB, int NBLK) {
  __shared__ uint2 ebuf[SMAX];
  __shared__ int hcnt[128];
  __shared__ int scn[128];
  __shared__ float dgs[128];
  int t = threadIdx.x;
  int b = blockIdx.x;
  if (t < 128) { hcnt[t] = 0; dgs[t] = 1.0f; }
  __syncthreads();
  int beg = cnts[b * NBLK];
  int end = cnts[b * NBLK + NBLK];
  for (int c = t; c < NBLK; c += 256) {
    int rel = cnts[b * NBLK + c] - beg;
    size_t sb = (size_t)c * (NB + 1) + b;
    int s0 = segs[sb], s1 = segs[sb + 1];
    int gsrc = c * CHUNK + s0;
    for (int k = 0; k < s1 - s0; ++k) {
      uint2 p = payloadA[gsrc + k];
      ebuf[rel + k] = p;
      atomicAdd(&hcnt[p.x & 127], 1);
      atomicAdd(&dgs[p.x & 127], __uint_as_float(p.y));
    }
  }
  __syncthreads();
  int v = (t < 128) ? hcnt[t] : 0;
  if (t < 128) scn[t] = v;
  __syncthreads();
  for (int off = 1; off < 128; off <<= 1) {
    int add = (t < 128 && t >= off) ? scn[t - off] : 0;
    __syncthreads();
    if (t < 128) scn[t] += add;
    __syncthreads();
  }
  int base = b * 128;
  if (t < 128) {
    int st = scn[t] - v;
    hcnt[t] = st;
    rs[base + t] = beg + st;
    int n = base + t;
    if (n < N) dis[n] = rsqrtf(dgs[t]);
  }
  if (t == 0) rs[base + 128] = end;
  __syncthreads();
  int sz = end - beg;
  for (int i = t; i < sz; i += 256) {
    uint2 p = ebuf[i];
    int pos = beg + atomicAdd(&hcnt[p.x & 127], 1);
    payloadB[pos] = make_uint2(p.x >> 7, p.y);
  }
}

__device__ __forceinline__ float blo(unsigned u) { return __uint_as_float(u << 16); }
__device__ __forceinline__ float bhi(unsigned u) { return __uint_as_float(u & 0xffff0000u); }
__device__ __forceinline__ unsigned pack2(float lo, float hi) {
  __hip_bfloat16 l = __float2bfloat16(lo), h = __float2bfloat16(hi);
  unsigned short ul = *reinterpret_cast<unsigned short*>(&l);
  unsigned short uh = *reinterpret_cast<unsigned short*>(&h);
  return (unsigned)ul | ((unsigned)uh << 16);
}

// ---- h1' = (x @ W1) * dis, FUSED: x staged bf16 in LDS (coalesced), 4 waves =
//      4 k-slices (W1 wave-uniform -> s_load), partials via LDS overlay. ----
__global__ void __launch_bounds__(256)
k_gemm1c(const float* __restrict__ x, const float* __restrict__ W1,
         const float* __restrict__ dis, uint4* __restrict__ hb1, int N) {
  __shared__ unsigned xs[GT * 257];   // 64 rows x 256 u32(=2 bf16) + pad; 65.8KB
  int t = threadIdx.x;
  int nb = blockIdx.x * GT;
  // stage: 8192 float4 over 256 threads = 32 each, coalesced
#pragma unroll 8
  for (int i = 0; i < 32; ++i) {
    int f = t + 256 * i;
    int row = f >> 7;                 // 128 float4 per row
    int off = f & 127;
    int n = nb + row;
    float4 v = make_float4(0.f, 0.f, 0.f, 0.f);
    if (n < N) v = *reinterpret_cast<const float4*>(x + (size_t)n * F_IN + off * 4);
    xs[row * 257 + off * 2]     = pack2(v.x, v.y);
    xs[row * 257 + off * 2 + 1] = pack2(v.z, v.w);
  }
  __syncthreads();
  int l = t & 63, s = t >> 6;         // node-in-tile, k-slice(wave)
  float acc[HID];
#pragma unroll
  for (int j = 0; j < HID; ++j) acc[j] = 0.0f;
  const unsigned* xrow = &xs[l * 257 + s * 64];
  const float* wbase = W1 + (size_t)(s * 128) * HID;
#pragma unroll 8
  for (int m = 0; m < 64; ++m) {
    unsigned u = xrow[m];             // banks (l+m)%32: 2 lanes/bank = free
    float x0 = blo(u), x1 = bhi(u);
    const float* w0 = wbase + (2 * m) * HID;
#pragma unroll
    for (int j = 0; j < HID; ++j) {
      acc[j] = fmaf(x0, w0[j], acc[j]);
      acc[j] = fmaf(x1, w0[HID + j], acc[j]);
    }
  }
  __syncthreads();                    // all xs reads done; overlay partials
  float* ps = reinterpret_cast<float*>(xs);  // ps[4][64][17] = 17.4KB
#pragma unroll
  for (int j = 0; j < HID; ++j) ps[(s * 64 + l) * 17 + j] = acc[j];
  __syncthreads();
  if (t < GT) {
    int n = nb + t;
    if (n < N) {
      float di = dis[n];
      float o[HID];
#pragma unroll
      for (int j = 0; j < HID; ++j)
        o[j] = (ps[t * 17 + j] + ps[(64 + t) * 17 + j] +
                ps[(128 + t) * 17 + j] + ps[(192 + t) * 17 + j]) * di;
      uint4 w0, w1;
      w0.x = pack2(o[0],  o[1]);  w0.y = pack2(o[2],  o[3]);
      w0.z = pack2(o[4],  o[5]);  w0.w = pack2(o[6],  o[7]);
      w1.x = pack2(o[8],  o[9]);  w1.y = pack2(o[10], o[11]);
      w1.z = pack2(o[12], o[13]); w1.w = pack2(o[14], o[15]);
      hb1[(size_t)n * 2]     = w0;
      hb1[(size_t)n * 2 + 1] = w1;
    }
  }
}

// ---- aggregation: ONE NODE PER LANE, TWO interleaved independent edge chains
//      (32 f32 register accumulators) for ~4x memory-level parallelism ----
template <int LAYER>
__global__ void __launch_bounds__(256)
k_aggn(const uint2* __restrict__ payload, const int* __restrict__ rs,
       const uint4* __restrict__ hb, const float* __restrict__ dis,
       const float* __restrict__ b1, uint4* __restrict__ hb2,
       float* __restrict__ g, int N) {
  int n = blockIdx.x * 256 + threadIdx.x;
  if (n >= N) return;
  int e0 = rs[n], e1 = rs[n + 1];
  int d = e1 - e0;
  int mid = e0 + (d >> 1);
  float a0 = 0, a1 = 0, a2 = 0, a3 = 0, a4 = 0, a5 = 0, a6 = 0, a7 = 0;
  float a8 = 0, a9 = 0, a10 = 0, a11 = 0, a12 = 0, a13 = 0, a14 = 0, a15 = 0;
  float c0 = 0, c1 = 0, c2 = 0, c3 = 0, c4 = 0, c5 = 0, c6 = 0, c7 = 0;
  float c8 = 0, c9 = 0, c10 = 0, c11 = 0, c12 = 0, c13 = 0, c14 = 0, c15 = 0;
  int eA = e0, eB = mid;
#pragma unroll 2
  for (; eA < mid; ++eA, ++eB) {
    uint2 pA = payload[eA];
    uint2 pB = payload[eB];
    const uint4* rowA = hb + ((size_t)pA.x * 2);
    const uint4* rowB = hb + ((size_t)pB.x * 2);
    uint4 rA0 = rowA[0], rA1 = rowA[1];
    uint4 rB0 = rowB[0], rB1 = rowB[1];
    float wA = __uint_as_float(pA.y), wB = __uint_as_float(pB.y);
    a0  = fmaf(blo(rA0.x), wA, a0);  a1  = fmaf(bhi(rA0.x), wA, a1);
    a2  = fmaf(blo(rA0.y), wA, a2);  a3  = fmaf(bhi(rA0.y), wA, a3);
    a4  = fmaf(blo(rA0.z), wA, a4);  a5  = fmaf(bhi(rA0.z), wA, a5);
    a6  = fmaf(blo(rA0.w), wA, a6);  a7  = fmaf(bhi(rA0.w), wA, a7);
    a8  = fmaf(blo(rA1.x), wA, a8);  a9  = fmaf(bhi(rA1.x), wA, a9);
    a10 = fmaf(blo(rA1.y), wA, a10); a11 = fmaf(bhi(rA1.y), wA, a11);
    a12 = fmaf(blo(rA1.z), wA, a12); a13 = fmaf(bhi(rA1.z), wA, a13);
    a14 = fmaf(blo(rA1.w), wA, a14); a15 = fmaf(bhi(rA1.w), wA, a15);
    c0  = fmaf(blo(rB0.x), wB, c0);  c1  = fmaf(bhi(rB0.x), wB, c1);
    c2  = fmaf(blo(rB0.y), wB, c2);  c3  = fmaf(bhi(rB0.y), wB, c3);
    c4  = fmaf(blo(rB0.z), wB, c4);  c5  = fmaf(bhi(rB0.z), wB, c5);
    c6  = fmaf(blo(rB0.w), wB, c6);  c7  = fmaf(bhi(rB0.w), wB, c7);
    c8  = fmaf(blo(rB1.x), wB, c8);  c9  = fmaf(bhi(rB1.x), wB, c9);
    c10 = fmaf(blo(rB1.y), wB, c10); c11 = fmaf(bhi(rB1.y), wB, c11);
    c12 = fmaf(blo(rB1.z), wB, c12); c13 = fmaf(bhi(rB1.z), wB, c13);
    c14 = fmaf(blo(rB1.w), wB, c14); c15 = fmaf(bhi(rB1.w), wB, c15);
  }
  if (eB < e1) {   // odd count: one leftover in chain B
    uint2 p = payload[eB];
    const uint4* row = hb + ((size_t)p.x * 2);
    uint4 r0 = row[0], r1 = row[1];
    float w = __uint_as_float(p.y);
    c0  = fmaf(blo(r0.x), w, c0);  c1  = fmaf(bhi(r0.x), w, c1);
    c2  = fmaf(blo(r0.y), w, c2);  c3  = fmaf(bhi(r0.y), w, c3);
    c4  = fmaf(blo(r0.z), w, c4);  c5  = fmaf(bhi(r0.z), w, c5);
    c6  = fmaf(blo(r0.w), w, c6);  c7  = fmaf(bhi(r0.w), w, c7);
    c8  = fmaf(blo(r1.x), w, c8);  c9  = fmaf(bhi(r1.x), w, c9);
    c10 = fmaf(blo(r1.y), w, c10); c11 = fmaf(bhi(r1.y), w, c11);
    c12 = fmaf(blo(r1.z), w, c12); c13 = fmaf(bhi(r1.z), w, c13);
    c14 = fmaf(blo(r1.w), w, c14); c15 = fmaf(bhi(r1.w), w, c15);
  }
  a0 += c0;  a1 += c1;  a2 += c2;  a3 += c3;
  a4 += c4;  a5 += c5;  a6 += c6;  a7 += c7;
  a8 += c8;  a9 += c9;  a10 += c10; a11 += c11;
  a12 += c12; a13 += c13; a14 += c14; a15 += c15;
  uint4 s0 = hb[(size_t)n * 2];
  uint4 s1 = hb[(size_t)n * 2 + 1];
  float di = dis[n];
  a0  = (a0  + blo(s0.x)) * di;  a1  = (a1  + bhi(s0.x)) * di;
  a2  = (a2  + blo(s0.y)) * di;  a3  = (a3  + bhi(s0.y)) * di;
  a4  = (a4  + blo(s0.z)) * di;  a5  = (a5  + bhi(s0.z)) * di;
  a6  = (a6  + blo(s0.w)) * di;  a7  = (a7  + bhi(s0.w)) * di;
  a8  = (a8  + blo(s1.x)) * di;  a9  = (a9  + bhi(s1.x)) * di;
  a10 = (a10 + blo(s1.y)) * di;  a11 = (a11 + bhi(s1.y)) * di;
  a12 = (a12 + blo(s1.z)) * di;  a13 = (a13 + bhi(s1.z)) * di;
  a14 = (a14 + blo(s1.w)) * di;  a15 = (a15 + bhi(s1.w)) * di;
  if (LAYER == 1) {
    a0  = fmaxf(a0  + b1[0],  0.0f) * di;  a1  = fmaxf(a1  + b1[1],  0.0f) * di;
    a2  = fmaxf(a2  + b1[2],  0.0f) * di;  a3  = fmaxf(a3  + b1[3],  0.0f) * di;
    a4  = fmaxf(a4  + b1[4],  0.0f) * di;  a5  = fmaxf(a5  + b1[5],  0.0f) * di;
    a6  = fmaxf(a6  + b1[6],  0.0f) * di;  a7  = fmaxf(a7  + b1[7],  0.0f) * di;
    a8  = fmaxf(a8  + b1[8],  0.0f) * di;  a9  = fmaxf(a9  + b1[9],  0.0f) * di;
    a10 = fmaxf(a10 + b1[10], 0.0f) * di;  a11 = fmaxf(a11 + b1[11], 0.0f) * di;
    a12 = fmaxf(a12 + b1[12], 0.0f) * di;  a13 = fmaxf(a13 + b1[13], 0.0f) * di;
    a14 = fmaxf(a14 + b1[14], 0.0f) * di;  a15 = fmaxf(a15 + b1[15], 0.0f) * di;
    uint4 w0, w1;
    w0.x = pack2(a0,  a1);  w0.y = pack2(a2,  a3);
    w0.z = pack2(a4,  a5);  w0.w = pack2(a6,  a7);
    w1.x = pack2(a8,  a9);  w1.y = pack2(a10, a11);
    w1.z = pack2(a12, a13); w1.w = pack2(a14, a15);
    hb2[(size_t)n * 2]     = w0;
    hb2[(size_t)n * 2 + 1] = w1;
  } else {
    float4* gr = reinterpret_cast<float4*>(g + (size_t)n * HID);
    gr[0] = make_float4(a0,  a1,  a2,  a3);
    gr[1] = make_float4(a4,  a5,  a6,  a7);
    gr[2] = make_float4(a8,  a9,  a10, a11);
    gr[3] = make_float4(a12, a13, a14, a15);
  }
}

// ---- out = log_softmax(g @ W2 + b2), thread-per-node ----
__global__ void k_out(const float* __restrict__ g, const float* __restrict__ W2,
                      const float* __restrict__ b2, float* __restrict__ out, int N) {
  int n = blockIdx.x * blockDim.x + threadIdx.x;
  if (n >= N) return;
  float gv[HID];
#pragma unroll
  for (int j = 0; j < HID; ++j) gv[j] = g[(size_t)n * HID + j];
  float o[NCLS];
#pragma unroll
  for (int c = 0; c < NCLS; ++c) o[c] = b2[c];
#pragma unroll
  for (int j = 0; j < HID; ++j) {
    float gj = gv[j];
    const float* wr = W2 + (size_t)j * NCLS;
#pragma unroll
    for (int c = 0; c < NCLS; ++c) o[c] = fmaf(gj, wr[c], o[c]);
  }
  float m = o[0];
#pragma unroll
  for (int c = 1; c < NCLS; ++c) m = fmaxf(m, o[c]);
  float ss = 0.0f;
#pragma unroll
  for (int c = 0; c < NCLS; ++c) ss += expf(o[c] - m);
  float lse = m + logf(ss);
  float* orow = out + (size_t)n * NCLS;
#pragma unroll
  for (int c = 0; c < NCLS; ++c) orow[c] = o[c] - lse;
}

extern "C" void kernel_launch(void* const* d_in, const int* in_sizes, int n_in,
                              void* d_out, int out_size, void* d_ws, size_t ws_size,
                              hipStream_t stream) {
  const float* x  = (const float*)d_in[0];
  const int*   ei = (const int*)d_in[1];
  const float* ew = (const float*)d_in[2];
  const float* W1 = (const float*)d_in[3];
  const float* b1 = (const float*)d_in[4];
  const float* W2 = (const float*)d_in[5];
  const float* b2 = (const float*)d_in[6];
  float* out = (float*)d_out;

  const int N = in_sizes[0] / F_IN;   // 100000
  const int E = in_sizes[2];          // 3200000
  const int* src = ei;
  const int* dst = ei + E;

  const int NB   = (N + 127) >> 7;             // 782 buckets
  const int NBLK = (E + CHUNK - 1) / CHUNK;    // 782 chunks
  const long long SCT = (long long)NB * NBLK + 1;
  const int Npad = (int)((SCT + 1023) & ~1023LL);
  const int nbScan = Npad / 1024;
  const int Nr   = (NB * 128 + 256 + 255) & ~255;
  const size_t SEGSZ = (size_t)NBLK * (NB + 1) + 4;

  // ws layout (4B words): counts[Npad] | bsum[1024] | dis[Nr] | rs[Nr] |
  //   hb1[N*8] | hb2[N*8] | g[N*16] | payloadA[2E] | segs[SEGSZ] | payloadB[2E]
  int* counts = (int*)d_ws;
  int* bsum   = counts + Npad;
  float* dis  = (float*)(bsum + 1024);
  int* rs     = (int*)(dis + Nr);
  uint4* hb1  = (uint4*)(rs + Nr);
  uint4* hb2  = hb1 + (size_t)N * 2;
  float* g    = (float*)(hb2 + (size_t)N * 2);
  uint2* payloadA = (uint2*)(g + (size_t)N * HID);
  int* segs   = (int*)(payloadA + (size_t)E);
  uint2* payloadB = (uint2*)(segs + SEGSZ);

  const int padLo = NB * NBLK;
  k_zpad<<<(Npad - padLo + 255) / 256, 256, 0, stream>>>(counts, padLo, Npad);
  k_count<<<NBLK, 256, 0, stream>>>(dst, counts, E, NB, NBLK);
  k_scanA<<<nbScan, 256, 0, stream>>>(counts, bsum);
  k_scanB<<<1, 1024, 0, stream>>>(bsum, nbScan);
  k_scanC<<<nbScan, 256, 0, stream>>>(counts, bsum);
  k_scat2<<<NBLK, 256, 0, stream>>>(src, dst, ew, payloadA, segs, E, NB);
  k_sortb2<<<NB, 256, 0, stream>>>(payloadA, segs, counts, payloadB, rs, dis, N, NB, NBLK);
  k_gemm1c<<<(N + GT - 1) / GT, 256, 0, stream>>>(x, W1, dis, hb1, N);
  k_aggn<1><<<(N + 255) / 256, 256, 0, stream>>>(payloadB, rs, hb1, dis, b1, hb2, nullptr, N);
  k_aggn<2><<<(N + 255) / 256, 256, 0, stream>>>(payloadB, rs, hb2, dis, nullptr, nullptr, g, N);
  k_out<<<(N + 255) / 256, 256, 0, stream>>>(g, W2, b2, out, N);
}

// Round 11
// 353.138 us; speedup vs baseline: 1.2582x; 1.2582x over previous
//
#include <hip/hip_runtime.h>
#include <hip/hip_bf16.h>

constexpr int F_IN  = 512;
constexpr int HID   = 16;
constexpr int NCLS  = 40;
constexpr int CHUNK = 4096;   // edges per chunk
constexpr int BMAX  = 800;    // max buckets (N=100000 -> NB=782)
constexpr int SMAX  = 6144;   // max edges per bucket
constexpr int NP    = 100096; // N padded to multiple of 128 (transpose tiles)

// ---- zero the scan pad [lo,hi) of counts ----
__global__ void k_zpad(int* __restrict__ counts, int lo, int hi) {
  int i = lo + blockIdx.x * 256 + threadIdx.x;
  if (i < hi) counts[i] = 0;
}

// ---- Pass A: per-chunk histogram of dst buckets (LDS atomics only) ----
__global__ void k_count(const int* __restrict__ dst, int* __restrict__ counts,
                        int E, int NB, int NBLK) {
  __shared__ int hist[BMAX];
  int t = threadIdx.x;
  for (int b = t; b < BMAX; b += 256) hist[b] = 0;
  __syncthreads();
  int base = blockIdx.x * CHUNK;
  for (int i = 0; i < CHUNK; i += 256) {
    int e = base + i + t;
    if (e < E) atomicAdd(&hist[dst[e] >> 7], 1);
  }
  __syncthreads();
  for (int b = t; b < NB; b += 256) counts[b * NBLK + blockIdx.x] = hist[b];
}

// ---- scan over counts (bucket-major), 3 stages, in-place ----
__global__ void k_scanA(const int* __restrict__ a, int* __restrict__ bsum) {
  __shared__ int sd[256];
  int t = threadIdx.x;
  int4 v = reinterpret_cast<const int4*>(a)[blockIdx.x * 256 + t];
  sd[t] = v.x + v.y + v.z + v.w;
  __syncthreads();
  for (int off = 128; off > 0; off >>= 1) {
    if (t < off) sd[t] += sd[t + off];
    __syncthreads();
  }
  if (!t) bsum[blockIdx.x] = sd[0];
}

__global__ void k_scanB(int* __restrict__ bsum, int nb) {
  __shared__ int sd[1024];
  int t = threadIdx.x;
  int v = (t < nb) ? bsum[t] : 0;
  sd[t] = v;
  __syncthreads();
  for (int off = 1; off < 1024; off <<= 1) {
    int add = (t >= off) ? sd[t - off] : 0;
    __syncthreads();
    sd[t] += add;
    __syncthreads();
  }
  if (t < nb) bsum[t] = sd[t] - v;  // exclusive
}

__global__ void k_scanC(int* __restrict__ a, const int* __restrict__ bsum) {
  __shared__ int sd[256];
  int t = threadIdx.x;
  int4 v = reinterpret_cast<int4*>(a)[blockIdx.x * 256 + t];
  int ts = v.x + v.y + v.z + v.w;
  sd[t] = ts;
  __syncthreads();
  for (int off = 1; off < 256; off <<= 1) {
    int add = (t >= off) ? sd[t - off] : 0;
    __syncthreads();
    sd[t] += add;
    __syncthreads();
  }
  int pre = bsum[blockIdx.x] + sd[t] - ts;
  int4 w;
  w.x = pre; w.y = pre + v.x; w.z = w.y + v.y; w.w = w.z + v.z;
  reinterpret_cast<int4*>(a)[blockIdx.x * 256 + t] = w;
}

// ---- Pass B: chunk-local LDS counting sort by bucket; STREAMING writes ----
__global__ void __launch_bounds__(256)
k_scat2(const int* __restrict__ src, const int* __restrict__ dst,
        const float* __restrict__ ew, uint2* __restrict__ payloadA,
        int* __restrict__ segs, int E, int NB) {
  __shared__ uint2 ebuf[CHUNK];
  __shared__ int hist[1024];
  __shared__ int sc[256];
  int t = threadIdx.x;
  int c = blockIdx.x;
  int cbase = c * CHUNK;
  int sz = min(CHUNK, E - cbase);
#pragma unroll
  for (int i = 0; i < 4; ++i) hist[t + 256 * i] = 0;
  __syncthreads();
  uint2 pk[16];
  int key[16];
#pragma unroll
  for (int r = 0; r < 16; ++r) {
    int i = r * 256 + t;
    int e = cbase + i;
    if (i < sz) {
      int s = src[e], d = dst[e];
      pk[r] = make_uint2(((unsigned)s << 7) | (unsigned)(d & 127),
                         __float_as_uint(ew[e]));
      key[r] = d >> 7;
      atomicAdd(&hist[key[r]], 1);
    } else {
      key[r] = -1;
    }
  }
  __syncthreads();
  int h0 = hist[4 * t], h1 = hist[4 * t + 1], h2 = hist[4 * t + 2], h3 = hist[4 * t + 3];
  int tsum = h0 + h1 + h2 + h3;
  sc[t] = tsum;
  __syncthreads();
  for (int off = 1; off < 256; off <<= 1) {
    int add = (t >= off) ? sc[t - off] : 0;
    __syncthreads();
    sc[t] += add;
    __syncthreads();
  }
  int pre = sc[t] - tsum;
  __syncthreads();
  hist[4 * t]     = pre;
  hist[4 * t + 1] = pre + h0;
  hist[4 * t + 2] = pre + h0 + h1;
  hist[4 * t + 3] = pre + h0 + h1 + h2;
  __syncthreads();
  size_t sb = (size_t)c * (NB + 1);
  for (int b = t; b < NB; b += 256) segs[sb + b] = hist[b];
  if (t == 0) segs[sb + NB] = sz;
  __syncthreads();
#pragma unroll
  for (int r = 0; r < 16; ++r) {
    if (key[r] >= 0) {
      int pos = atomicAdd(&hist[key[r]], 1);
      ebuf[pos] = pk[r];
    }
  }
  __syncthreads();
  for (int i = t; i < sz; i += 256) payloadA[cbase + i] = ebuf[i];
}

// ---- Pass C: per-bucket assembly + node counting sort; streaming writes ----
__global__ void __launch_bounds__(256)
k_sortb2(const uint2* __restrict__ payloadA, const int* __restrict__ segs,
         const int* __restrict__ cnts, uint2* __restrict__ payloadB,
         int* __restrict__ rs, float* __restrict__ dis,
         int N, int NB, int NBLK) {
  __shared__ uint2 ebuf[SMAX];
  __shared__ int hcnt[128];
  __shared__ int scn[128];
  __shared__ float dgs[128];
  int t = threadIdx.x;
  int b = blockIdx.x;
  if (t < 128) { hcnt[t] = 0; dgs[t] = 1.0f; }
  __syncthreads();
  int beg = cnts[b * NBLK];
  int end = cnts[b * NBLK + NBLK];
  for (int c = t; c < NBLK; c += 256) {
    int rel = cnts[b * NBLK + c] - beg;
    size_t sb = (size_t)c * (NB + 1) + b;
    int s0 = segs[sb], s1 = segs[sb + 1];
    int gsrc = c * CHUNK + s0;
    for (int k = 0; k < s1 - s0; ++k) {
      uint2 p = payloadA[gsrc + k];
      ebuf[rel + k] = p;
      atomicAdd(&hcnt[p.x & 127], 1);
      atomicAdd(&dgs[p.x & 127], __uint_as_float(p.y));
    }
  }
  __syncthreads();
  int v = (t < 128) ? hcnt[t] : 0;
  if (t < 128) scn[t] = v;
  __syncthreads();
  for (int off = 1; off < 128; off <<= 1) {
    int add = (t < 128 && t >= off) ? scn[t - off] : 0;
    __syncthreads();
    if (t < 128) scn[t] += add;
    __syncthreads();
  }
  int base = b * 128;
  if (t < 128) {
    int st = scn[t] - v;
    hcnt[t] = st;
    rs[base + t] = beg + st;
    int n = base + t;
    if (n < N) dis[n] = rsqrtf(dgs[t]);
  }
  if (t == 0) rs[base + 128] = end;
  __syncthreads();
  int sz = end - beg;
  for (int i = t; i < sz; i += 256) {
    uint2 p = ebuf[i];
    int pos = beg + atomicAdd(&hcnt[p.x & 127], 1);
    payloadB[pos] = make_uint2(p.x >> 7, p.y);
  }
}

__device__ __forceinline__ float blo(unsigned u) { return __uint_as_float(u << 16); }
__device__ __forceinline__ float bhi(unsigned u) { return __uint_as_float(u & 0xffff0000u); }
__device__ __forceinline__ unsigned pack2(float lo, float hi) {
  __hip_bfloat16 l = __float2bfloat16(lo), h = __float2bfloat16(hi);
  unsigned short ul = *reinterpret_cast<unsigned short*>(&l);
  unsigned short uh = *reinterpret_cast<unsigned short*>(&h);
  return (unsigned)ul | ((unsigned)uh << 16);
}

// ---- transpose x[N][512] f32 -> xT[512][NP] bf16, tiles 128n x 64k ----
__global__ void __launch_bounds__(256)
k_xpose(const float* __restrict__ x, unsigned* __restrict__ xtb32, int N) {
  __shared__ float tile[128 * 65];
  int t = threadIdx.x;
  int nb = (blockIdx.x >> 3) * 128;
  int k0 = (blockIdx.x & 7) * 64;
#pragma unroll
  for (int i = 0; i < 8; ++i) {
    int f = t + 256 * i;
    int rr = f >> 4;
    int off = f & 15;
    int n = nb + rr;
    float4 v = make_float4(0.f, 0.f, 0.f, 0.f);
    if (n < N) v = *reinterpret_cast<const float4*>(x + (size_t)n * F_IN + k0 + off * 4);
    int c = off * 4;
    tile[rr * 65 + c + 0] = v.x;
    tile[rr * 65 + c + 1] = v.y;
    tile[rr * 65 + c + 2] = v.z;
    tile[rr * 65 + c + 3] = v.w;
  }
  __syncthreads();
  int l = t & 63, wv = t >> 6;
#pragma unroll
  for (int p = 0; p < 16; ++p) {
    int kk = wv * 16 + p;
    unsigned u = pack2(tile[(2 * l) * 65 + kk], tile[(2 * l + 1) * 65 + kk]);
    xtb32[(size_t)(k0 + kk) * (NP / 2) + (nb >> 1) + l] = u;
  }
}

// ---- h1' = (x @ W1) * dis, from xT(bf16): fully coalesced ----
__global__ void __launch_bounds__(256)
k_gemm1b(const unsigned* __restrict__ xtb32, const float* __restrict__ W1,
         const float* __restrict__ dis, uint4* __restrict__ hb1, int N) {
  __shared__ float ps[4 * 128 * 17];
  int t = threadIdx.x;
  int l = t & 63, s = t >> 6;
  int nb = blockIdx.x * 128;
  const unsigned* xp = xtb32 + (size_t)(s * 128) * (NP / 2) + (nb >> 1) + l;
  const float* wp = W1 + s * 128 * HID;
  float a0[HID], a1[HID];
#pragma unroll
  for (int j = 0; j < HID; ++j) { a0[j] = 0.0f; a1[j] = 0.0f; }
#pragma unroll 4
  for (int kk = 0; kk < 128; ++kk) {
    unsigned u = xp[(size_t)kk * (NP / 2)];
    float x0 = blo(u), x1 = bhi(u);
    const float* wr = wp + kk * HID;
#pragma unroll
    for (int j = 0; j < HID; ++j) {
      float w = wr[j];
      a0[j] = fmaf(x0, w, a0[j]);
      a1[j] = fmaf(x1, w, a1[j]);
    }
  }
#pragma unroll
  for (int j = 0; j < HID; ++j) {
    ps[(s * 128 + 2 * l) * 17 + j]     = a0[j];
    ps[(s * 128 + 2 * l + 1) * 17 + j] = a1[j];
  }
  __syncthreads();
  if (t < 128) {
    int n = nb + t;
    if (n < N) {
      float di = dis[n];
      float o[HID];
#pragma unroll
      for (int j = 0; j < HID; ++j)
        o[j] = (ps[t * 17 + j] + ps[(128 + t) * 17 + j] +
                ps[(256 + t) * 17 + j] + ps[(384 + t) * 17 + j]) * di;
      uint4 w0, w1;
      w0.x = pack2(o[0],  o[1]);  w0.y = pack2(o[2],  o[3]);
      w0.z = pack2(o[4],  o[5]);  w0.w = pack2(o[6],  o[7]);
      w1.x = pack2(o[8],  o[9]);  w1.y = pack2(o[10], o[11]);
      w1.z = pack2(o[12], o[13]); w1.w = pack2(o[14], o[15]);
      hb1[(size_t)n * 2]     = w0;
      hb1[(size_t)n * 2 + 1] = w1;
    }
  }
}

// ---- fallback gemm: thread-per-row (used if ws too small) ----
__global__ void k_gemm1(const float* __restrict__ x, const float* __restrict__ W1,
                        const float* __restrict__ dis, uint4* __restrict__ hb1, int N) {
  int n = blockIdx.x * blockDim.x + threadIdx.x;
  if (n >= N) return;
  const float* xr = x + (size_t)n * F_IN;
  float acc[HID];
#pragma unroll
  for (int j = 0; j < HID; ++j) acc[j] = 0.0f;
  for (int k = 0; k < F_IN; k += 16) {
    float4 q0 = *reinterpret_cast<const float4*>(xr + k);
    float4 q1 = *reinterpret_cast<const float4*>(xr + k + 4);
    float4 q2 = *reinterpret_cast<const float4*>(xr + k + 8);
    float4 q3 = *reinterpret_cast<const float4*>(xr + k + 12);
    float xv[16] = {q0.x, q0.y, q0.z, q0.w, q1.x, q1.y, q1.z, q1.w,
                    q2.x, q2.y, q2.z, q2.w, q3.x, q3.y, q3.z, q3.w};
#pragma unroll
    for (int kk = 0; kk < 16; ++kk) {
      float xx = xv[kk];
      const float* wr = W1 + (size_t)(k + kk) * HID;
#pragma unroll
      for (int j = 0; j < HID; ++j) acc[j] = fmaf(xx, wr[j], acc[j]);
    }
  }
  float di = dis[n];
  uint4 w0, w1;
  w0.x = pack2(acc[0] * di,  acc[1] * di);  w0.y = pack2(acc[2] * di,  acc[3] * di);
  w0.z = pack2(acc[4] * di,  acc[5] * di);  w0.w = pack2(acc[6] * di,  acc[7] * di);
  w1.x = pack2(acc[8] * di,  acc[9] * di);  w1.y = pack2(acc[10] * di, acc[11] * di);
  w1.z = pack2(acc[12] * di, acc[13] * di); w1.w = pack2(acc[14] * di, acc[15] * di);
  hb1[(size_t)n * 2]     = w0;
  hb1[(size_t)n * 2 + 1] = w1;
}

// ---- aggregation: ONE NODE PER LANE, TWO interleaved independent edge chains
//      (32 f32 register accumulators) for ~4x memory-level parallelism ----
template <int LAYER>
__global__ void __launch_bounds__(256)
k_aggn(const uint2* __restrict__ payload, const int* __restrict__ rs,
       const uint4* __restrict__ hb, const float* __restrict__ dis,
       const float* __restrict__ b1, uint4* __restrict__ hb2,
       float* __restrict__ g, int N) {
  int n = blockIdx.x * 256 + threadIdx.x;
  if (n >= N) return;
  int e0 = rs[n], e1 = rs[n + 1];
  int d = e1 - e0;
  int mid = e0 + (d >> 1);
  float a0 = 0, a1 = 0, a2 = 0, a3 = 0, a4 = 0, a5 = 0, a6 = 0, a7 = 0;
  float a8 = 0, a9 = 0, a10 = 0, a11 = 0, a12 = 0, a13 = 0, a14 = 0, a15 = 0;
  float c0 = 0, c1 = 0, c2 = 0, c3 = 0, c4 = 0, c5 = 0, c6 = 0, c7 = 0;
  float c8 = 0, c9 = 0, c10 = 0, c11 = 0, c12 = 0, c13 = 0, c14 = 0, c15 = 0;
  int eA = e0, eB = mid;
#pragma unroll 2
  for (; eA < mid; ++eA, ++eB) {
    uint2 pA = payload[eA];
    uint2 pB = payload[eB];
    const uint4* rowA = hb + ((size_t)pA.x * 2);
    const uint4* rowB = hb + ((size_t)pB.x * 2);
    uint4 rA0 = rowA[0], rA1 = rowA[1];
    uint4 rB0 = rowB[0], rB1 = rowB[1];
    float wA = __uint_as_float(pA.y), wB = __uint_as_float(pB.y);
    a0  = fmaf(blo(rA0.x), wA, a0);  a1  = fmaf(bhi(rA0.x), wA, a1);
    a2  = fmaf(blo(rA0.y), wA, a2);  a3  = fmaf(bhi(rA0.y), wA, a3);
    a4  = fmaf(blo(rA0.z), wA, a4);  a5  = fmaf(bhi(rA0.z), wA, a5);
    a6  = fmaf(blo(rA0.w), wA, a6);  a7  = fmaf(bhi(rA0.w), wA, a7);
    a8  = fmaf(blo(rA1.x), wA, a8);  a9  = fmaf(bhi(rA1.x), wA, a9);
    a10 = fmaf(blo(rA1.y), wA, a10); a11 = fmaf(bhi(rA1.y), wA, a11);
    a12 = fmaf(blo(rA1.z), wA, a12); a13 = fmaf(bhi(rA1.z), wA, a13);
    a14 = fmaf(blo(rA1.w), wA, a14); a15 = fmaf(bhi(rA1.w), wA, a15);
    c0  = fmaf(blo(rB0.x), wB, c0);  c1  = fmaf(bhi(rB0.x), wB, c1);
    c2  = fmaf(blo(rB0.y), wB, c2);  c3  = fmaf(bhi(rB0.y), wB, c3);
    c4  = fmaf(blo(rB0.z), wB, c4);  c5  = fmaf(bhi(rB0.z), wB, c5);
    c6  = fmaf(blo(rB0.w), wB, c6);  c7  = fmaf(bhi(rB0.w), wB, c7);
    c8  = fmaf(blo(rB1.x), wB, c8);  c9  = fmaf(bhi(rB1.x), wB, c9);
    c10 = fmaf(blo(rB1.y), wB, c10); c11 = fmaf(bhi(rB1.y), wB, c11);
    c12 = fmaf(blo(rB1.z), wB, c12); c13 = fmaf(bhi(rB1.z), wB, c13);
    c14 = fmaf(blo(rB1.w), wB, c14); c15 = fmaf(bhi(rB1.w), wB, c15);
  }
  if (eB < e1) {
    uint2 p = payload[eB];
    const uint4* row = hb + ((size_t)p.x * 2);
    uint4 r0 = row[0], r1 = row[1];
    float w = __uint_as_float(p.y);
    c0  = fmaf(blo(r0.x), w, c0);  c1  = fmaf(bhi(r0.x), w, c1);
    c2  = fmaf(blo(r0.y), w, c2);  c3  = fmaf(bhi(r0.y), w, c3);
    c4  = fmaf(blo(r0.z), w, c4);  c5  = fmaf(bhi(r0.z), w, c5);
    c6  = fmaf(blo(r0.w), w, c6);  c7  = fmaf(bhi(r0.w), w, c7);
    c8  = fmaf(blo(r1.x), w, c8);  c9  = fmaf(bhi(r1.x), w, c9);
    c10 = fmaf(blo(r1.y), w, c10); c11 = fmaf(bhi(r1.y), w, c11);
    c12 = fmaf(blo(r1.z), w, c12); c13 = fmaf(bhi(r1.z), w, c13);
    c14 = fmaf(blo(r1.w), w, c14); c15 = fmaf(bhi(r1.w), w, c15);
  }
  a0 += c0;  a1 += c1;  a2 += c2;  a3 += c3;
  a4 += c4;  a5 += c5;  a6 += c6;  a7 += c7;
  a8 += c8;  a9 += c9;  a10 += c10; a11 += c11;
  a12 += c12; a13 += c13; a14 += c14; a15 += c15;
  uint4 s0 = hb[(size_t)n * 2];
  uint4 s1 = hb[(size_t)n * 2 + 1];
  float di = dis[n];
  a0  = (a0  + blo(s0.x)) * di;  a1  = (a1  + bhi(s0.x)) * di;
  a2  = (a2  + blo(s0.y)) * di;  a3  = (a3  + bhi(s0.y)) * di;
  a4  = (a4  + blo(s0.z)) * di;  a5  = (a5  + bhi(s0.z)) * di;
  a6  = (a6  + blo(s0.w)) * di;  a7  = (a7  + bhi(s0.w)) * di;
  a8  = (a8  + blo(s1.x)) * di;  a9  = (a9  + bhi(s1.x)) * di;
  a10 = (a10 + blo(s1.y)) * di;  a11 = (a11 + bhi(s1.y)) * di;
  a12 = (a12 + blo(s1.z)) * di;  a13 = (a13 + bhi(s1.z)) * di;
  a14 = (a14 + blo(s1.w)) * di;  a15 = (a15 + bhi(s1.w)) * di;
  if (LAYER == 1) {
    a0  = fmaxf(a0  + b1[0],  0.0f) * di;  a1  = fmaxf(a1  + b1[1],  0.0f) * di;
    a2  = fmaxf(a2  + b1[2],  0.0f) * di;  a3  = fmaxf(a3  + b1[3],  0.0f) * di;
    a4  = fmaxf(a4  + b1[4],  0.0f) * di;  a5  = fmaxf(a5  + b1[5],  0.0f) * di;
    a6  = fmaxf(a6  + b1[6],  0.0f) * di;  a7  = fmaxf(a7  + b1[7],  0.0f) * di;
    a8  = fmaxf(a8  + b1[8],  0.0f) * di;  a9  = fmaxf(a9  + b1[9],  0.0f) * di;
    a10 = fmaxf(a10 + b1[10], 0.0f) * di;  a11 = fmaxf(a11 + b1[11], 0.0f) * di;
    a12 = fmaxf(a12 + b1[12], 0.0f) * di;  a13 = fmaxf(a13 + b1[13], 0.0f) * di;
    a14 = fmaxf(a14 + b1[14], 0.0f) * di;  a15 = fmaxf(a15 + b1[15], 0.0f) * di;
    uint4 w0, w1;
    w0.x = pack2(a0,  a1);  w0.y = pack2(a2,  a3);
    w0.z = pack2(a4,  a5);  w0.w = pack2(a6,  a7);
    w1.x = pack2(a8,  a9);  w1.y = pack2(a10, a11);
    w1.z = pack2(a12, a13); w1.w = pack2(a14, a15);
    hb2[(size_t)n * 2]     = w0;
    hb2[(size_t)n * 2 + 1] = w1;
  } else {
    float4* gr = reinterpret_cast<float4*>(g + (size_t)n * HID);
    gr[0] = make_float4(a0,  a1,  a2,  a3);
    gr[1] = make_float4(a4,  a5,  a6,  a7);
    gr[2] = make_float4(a8,  a9,  a10, a11);
    gr[3] = make_float4(a12, a13, a14, a15);
  }
}

// ---- out = log_softmax(g @ W2 + b2), thread-per-node ----
__global__ void k_out(const float* __restrict__ g, const float* __restrict__ W2,
                      const float* __restrict__ b2, float* __restrict__ out, int N) {
  int n = blockIdx.x * blockDim.x + threadIdx.x;
  if (n >= N) return;
  float gv[HID];
#pragma unroll
  for (int j = 0; j < HID; ++j) gv[j] = g[(size_t)n * HID + j];
  float o[NCLS];
#pragma unroll
  for (int c = 0; c < NCLS; ++c) o[c] = b2[c];
#pragma unroll
  for (int j = 0; j < HID; ++j) {
    float gj = gv[j];
    const float* wr = W2 + (size_t)j * NCLS;
#pragma unroll
    for (int c = 0; c < NCLS; ++c) o[c] = fmaf(gj, wr[c], o[c]);
  }
  float m = o[0];
#pragma unroll
  for (int c = 1; c < NCLS; ++c) m = fmaxf(m, o[c]);
  float ss = 0.0f;
#pragma unroll
  for (int c = 0; c < NCLS; ++c) ss += expf(o[c] - m);
  float lse = m + logf(ss);
  float* orow = out + (size_t)n * NCLS;
#pragma unroll
  for (int c = 0; c < NCLS; ++c) orow[c] = o[c] - lse;
}

extern "C" void kernel_launch(void* const* d_in, const int* in_sizes, int n_in,
                              void* d_out, int out_size, void* d_ws, size_t ws_size,
                              hipStream_t stream) {
  const float* x  = (const float*)d_in[0];
  const int*   ei = (const int*)d_in[1];
  const float* ew = (const float*)d_in[2];
  const float* W1 = (const float*)d_in[3];
  const float* b1 = (const float*)d_in[4];
  const float* W2 = (const float*)d_in[5];
  const float* b2 = (const float*)d_in[6];
  float* out = (float*)d_out;

  const int N = in_sizes[0] / F_IN;   // 100000
  const int E = in_sizes[2];          // 3200000
  const int* src = ei;
  const int* dst = ei + E;

  const int NB   = (N + 127) >> 7;             // 782 buckets
  const int NBLK = (E + CHUNK - 1) / CHUNK;    // 782 chunks
  const long long SCT = (long long)NB * NBLK + 1;
  const int Npad = (int)((SCT + 1023) & ~1023LL);
  const int nbScan = Npad / 1024;
  const int Nr   = (NB * 128 + 256 + 255) & ~255;
  const size_t SEGSZ = (size_t)NBLK * (NB + 1) + 4;

  // ws layout (4B words): counts[Npad] | bsum[1024] | dis[Nr] | rs[Nr] |
  //   hb1[N*8] | hb2[N*8] | g[N*16] | payloadA[2E] | segs[SEGSZ] | payloadB[2E] | xtb[NP*256]
  int* counts = (int*)d_ws;
  int* bsum   = counts + Npad;
  float* dis  = (float*)(bsum + 1024);
  int* rs     = (int*)(dis + Nr);
  uint4* hb1  = (uint4*)(rs + Nr);
  uint4* hb2  = hb1 + (size_t)N * 2;
  float* g    = (float*)(hb2 + (size_t)N * 2);
  uint2* payloadA = (uint2*)(g + (size_t)N * HID);
  int* segs   = (int*)(payloadA + (size_t)E);
  uint2* payloadB = (uint2*)(segs + SEGSZ);
  unsigned* xtb32 = (unsigned*)(payloadB + (size_t)E);
  size_t need = ((char*)(xtb32 + (size_t)NP * F_IN / 2)) - (char*)d_ws;
  bool fast = (ws_size >= need);

  const int padLo = NB * NBLK;
  k_zpad<<<(Npad - padLo + 255) / 256, 256, 0, stream>>>(counts, padLo, Npad);
  k_count<<<NBLK, 256, 0, stream>>>(dst, counts, E, NB, NBLK);
  k_scanA<<<nbScan, 256, 0, stream>>>(counts, bsum);
  k_scanB<<<1, 1024, 0, stream>>>(bsum, nbScan);
  k_scanC<<<nbScan, 256, 0, stream>>>(counts, bsum);
  k_scat2<<<NBLK, 256, 0, stream>>>(src, dst, ew, payloadA, segs, E, NB);
  k_sortb2<<<NB, 256, 0, stream>>>(payloadA, segs, counts, payloadB, rs, dis, N, NB, NBLK);
  if (fast) {
    k_xpose<<<(NP / 128) * 8, 256, 0, stream>>>(x, xtb32, N);
    k_gemm1b<<<NP / 128, 256, 0, stream>>>(xtb32, W1, dis, hb1, N);
  } else {
    k_gemm1<<<(N + 255) / 256, 256, 0, stream>>>(x, W1, dis, hb1, N);
  }
  k_aggn<1><<<(N + 255) / 256, 256, 0, stream>>>(payloadB, rs, hb1, dis, b1, hb2, nullptr, N);
  k_aggn<2><<<(N + 255) / 256, 256, 0, stream>>>(payloadB, rs, hb2, dis, nullptr, nullptr, g, N);
  k_out<<<(N + 255) / 256, 256, 0, stream>>>(g, W2, b2, out, N);
}

// Round 12
// 330.913 us; speedup vs baseline: 1.3427x; 1.0672x over previous
//
#include <hip/hip_runtime.h>
#include <hip/hip_bf16.h>

constexpr int F_IN  = 512;
constexpr int HID   = 16;
constexpr int NCLS  = 40;
constexpr int CHUNK = 4096;   // edges per chunk
constexpr int BMAX  = 800;    // max buckets (N=100000 -> NB=782)
constexpr int SMAX  = 6144;   // max edges per bucket

// ---- zero the scan pad [lo,hi) of counts ----
__global__ void k_zpad(int* __restrict__ counts, int lo, int hi) {
  int i = lo + blockIdx.x * 256 + threadIdx.x;
  if (i < hi) counts[i] = 0;
}

// ---- Pass A: per-chunk histogram of dst buckets (LDS atomics only) ----
__global__ void k_count(const int* __restrict__ dst, int* __restrict__ counts,
                        int E, int NB, int NBLK) {
  __shared__ int hist[BMAX];
  int t = threadIdx.x;
  for (int b = t; b < BMAX; b += 256) hist[b] = 0;
  __syncthreads();
  int base = blockIdx.x * CHUNK;
  for (int i = 0; i < CHUNK; i += 256) {
    int e = base + i + t;
    if (e < E) atomicAdd(&hist[dst[e] >> 7], 1);
  }
  __syncthreads();
  for (int b = t; b < NB; b += 256) counts[b * NBLK + blockIdx.x] = hist[b];
}

// ---- scan over counts (bucket-major), 3 stages, in-place ----
__global__ void k_scanA(const int* __restrict__ a, int* __restrict__ bsum) {
  __shared__ int sd[256];
  int t = threadIdx.x;
  int4 v = reinterpret_cast<const int4*>(a)[blockIdx.x * 256 + t];
  sd[t] = v.x + v.y + v.z + v.w;
  __syncthreads();
  for (int off = 128; off > 0; off >>= 1) {
    if (t < off) sd[t] += sd[t + off];
    __syncthreads();
  }
  if (!t) bsum[blockIdx.x] = sd[0];
}

__global__ void k_scanB(int* __restrict__ bsum, int nb) {
  __shared__ int sd[1024];
  int t = threadIdx.x;
  int v = (t < nb) ? bsum[t] : 0;
  sd[t] = v;
  __syncthreads();
  for (int off = 1; off < 1024; off <<= 1) {
    int add = (t >= off) ? sd[t - off] : 0;
    __syncthreads();
    sd[t] += add;
    __syncthreads();
  }
  if (t < nb) bsum[t] = sd[t] - v;  // exclusive
}

__global__ void k_scanC(int* __restrict__ a, const int* __restrict__ bsum) {
  __shared__ int sd[256];
  int t = threadIdx.x;
  int4 v = reinterpret_cast<int4*>(a)[blockIdx.x * 256 + t];
  int ts = v.x + v.y + v.z + v.w;
  sd[t] = ts;
  __syncthreads();
  for (int off = 1; off < 256; off <<= 1) {
    int add = (t >= off) ? sd[t - off] : 0;
    __syncthreads();
    sd[t] += add;
    __syncthreads();
  }
  int pre = bsum[blockIdx.x] + sd[t] - ts;
  int4 w;
  w.x = pre; w.y = pre + v.x; w.z = w.y + v.y; w.w = w.z + v.z;
  reinterpret_cast<int4*>(a)[blockIdx.x * 256 + t] = w;
}

// ---- Pass B: chunk-local LDS counting sort by bucket; STREAMING writes ----
__global__ void __launch_bounds__(256)
k_scat2(const int* __restrict__ src, const int* __restrict__ dst,
        const float* __restrict__ ew, uint2* __restrict__ payloadA,
        int* __restrict__ segs, int E, int NB) {
  __shared__ uint2 ebuf[CHUNK];
  __shared__ int hist[1024];
  __shared__ int sc[256];
  int t = threadIdx.x;
  int c = blockIdx.x;
  int cbase = c * CHUNK;
  int sz = min(CHUNK, E - cbase);
#pragma unroll
  for (int i = 0; i < 4; ++i) hist[t + 256 * i] = 0;
  __syncthreads();
  uint2 pk[16];
  int key[16];
#pragma unroll
  for (int r = 0; r < 16; ++r) {
    int i = r * 256 + t;
    int e = cbase + i;
    if (i < sz) {
      int s = src[e], d = dst[e];
      pk[r] = make_uint2(((unsigned)s << 7) | (unsigned)(d & 127),
                         __float_as_uint(ew[e]));
      key[r] = d >> 7;
      atomicAdd(&hist[key[r]], 1);
    } else {
      key[r] = -1;
    }
  }
  __syncthreads();
  int h0 = hist[4 * t], h1 = hist[4 * t + 1], h2 = hist[4 * t + 2], h3 = hist[4 * t + 3];
  int tsum = h0 + h1 + h2 + h3;
  sc[t] = tsum;
  __syncthreads();
  for (int off = 1; off < 256; off <<= 1) {
    int add = (t >= off) ? sc[t - off] : 0;
    __syncthreads();
    sc[t] += add;
    __syncthreads();
  }
  int pre = sc[t] - tsum;
  __syncthreads();
  hist[4 * t]     = pre;
  hist[4 * t + 1] = pre + h0;
  hist[4 * t + 2] = pre + h0 + h1;
  hist[4 * t + 3] = pre + h0 + h1 + h2;
  __syncthreads();
  size_t sb = (size_t)c * (NB + 1);
  for (int b = t; b < NB; b += 256) segs[sb + b] = hist[b];
  if (t == 0) segs[sb + NB] = sz;
  __syncthreads();
#pragma unroll
  for (int r = 0; r < 16; ++r) {
    if (key[r] >= 0) {
      int pos = atomicAdd(&hist[key[r]], 1);
      ebuf[pos] = pk[r];
    }
  }
  __syncthreads();
  for (int i = t; i < sz; i += 256) payloadA[cbase + i] = ebuf[i];
}

// ---- Pass C: per-bucket assembly + node counting sort; streaming writes ----
__global__ void __launch_bounds__(256)
k_sortb2(const uint2* __restrict__ payloadA, const int* __restrict__ segs,
         const int* __restrict__ cnts, uint2* __restrict__ payloadB,
         int* __restrict__ rs, float* __restrict__ dis,
         int N, int NB, int NBLK) {
  __shared__ uint2 ebuf[SMAX];
  __shared__ int hcnt[128];
  __shared__ int scn[128];
  __shared__ float dgs[128];
  int t = threadIdx.x;
  int b = blockIdx.x;
  if (t < 128) { hcnt[t] = 0; dgs[t] = 1.0f; }
  __syncthreads();
  int beg = cnts[b * NBLK];
  int end = cnts[b * NBLK + NBLK];
  for (int c = t; c < NBLK; c += 256) {
    int rel = cnts[b * NBLK + c] - beg;
    size_t sb = (size_t)c * (NB + 1) + b;
    int s0 = segs[sb], s1 = segs[sb + 1];
    int gsrc = c * CHUNK + s0;
    for (int k = 0; k < s1 - s0; ++k) {
      uint2 p = payloadA[gsrc + k];
      ebuf[rel + k] = p;
      atomicAdd(&hcnt[p.x & 127], 1);
      atomicAdd(&dgs[p.x & 127], __uint_as_float(p.y));
    }
  }
  __syncthreads();
  int v = (t < 128) ? hcnt[t] : 0;
  if (t < 128) scn[t] = v;
  __syncthreads();
  for (int off = 1; off < 128; off <<= 1) {
    int add = (t < 128 && t >= off) ? scn[t - off] : 0;
    __syncthreads();
    if (t < 128) scn[t] += add;
    __syncthreads();
  }
  int base = b * 128;
  if (t < 128) {
    int st = scn[t] - v;
    hcnt[t] = st;
    rs[base + t] = beg + st;
    int n = base + t;
    if (n < N) dis[n] = rsqrtf(dgs[t]);
  }
  if (t == 0) rs[base + 128] = end;
  __syncthreads();
  int sz = end - beg;
  for (int i = t; i < sz; i += 256) {
    uint2 p = ebuf[i];
    int pos = beg + atomicAdd(&hcnt[p.x & 127], 1);
    payloadB[pos] = make_uint2(p.x >> 7, p.y);
  }
}

__device__ __forceinline__ float blo(unsigned u) { return __uint_as_float(u << 16); }
__device__ __forceinline__ float bhi(unsigned u) { return __uint_as_float(u & 0xffff0000u); }
__device__ __forceinline__ unsigned pack2(float lo, float hi) {
  __hip_bfloat16 l = __float2bfloat16(lo), h = __float2bfloat16(hi);
  unsigned short ul = *reinterpret_cast<unsigned short*>(&l);
  unsigned short uh = *reinterpret_cast<unsigned short*>(&h);
  return (unsigned)ul | ((unsigned)uh << 16);
}

// ---- h1' = (x @ W1) * dis, K split 4-ways across waves (thread = row x K-quarter),
//      direct from x (no transpose); combine via stride-17 LDS. Grid = 1563 blocks. ----
__global__ void __launch_bounds__(256)
k_gemm1d(const float* __restrict__ x, const float* __restrict__ W1,
         const float* __restrict__ dis, uint4* __restrict__ hb1, int N) {
  __shared__ float ps[4 * 64 * 17];   // 17.4 KB
  int t = threadIdx.x;
  int r = t & 63, s = t >> 6;
  int nb = blockIdx.x * 64;
  int n = nb + r;
  float acc[HID];
#pragma unroll
  for (int j = 0; j < HID; ++j) acc[j] = 0.0f;
  if (n < N) {
    const float* xr = x + (size_t)n * F_IN + s * 128;
    const float* wp = W1 + (size_t)(s * 128) * HID;
#pragma unroll 4
    for (int c = 0; c < 32; ++c) {            // 32 x float4 = 128 floats
      float4 v = *reinterpret_cast<const float4*>(xr + c * 4);
      const float* wr = wp + (c * 4) * HID;
#pragma unroll
      for (int j = 0; j < HID; ++j) {
        acc[j] = fmaf(v.x, wr[j], acc[j]);
        acc[j] = fmaf(v.y, wr[HID + j], acc[j]);
        acc[j] = fmaf(v.z, wr[2 * HID + j], acc[j]);
        acc[j] = fmaf(v.w, wr[3 * HID + j], acc[j]);
      }
    }
  }
#pragma unroll
  for (int j = 0; j < HID; ++j) ps[(s * 64 + r) * 17 + j] = acc[j];
  __syncthreads();
  if (t < 64) {
    if (n < N) {
      float di = dis[n];
      float o[HID];
#pragma unroll
      for (int j = 0; j < HID; ++j)
        o[j] = (ps[t * 17 + j] + ps[(64 + t) * 17 + j] +
                ps[(128 + t) * 17 + j] + ps[(192 + t) * 17 + j]) * di;
      uint4 w0, w1;
      w0.x = pack2(o[0],  o[1]);  w0.y = pack2(o[2],  o[3]);
      w0.z = pack2(o[4],  o[5]);  w0.w = pack2(o[6],  o[7]);
      w1.x = pack2(o[8],  o[9]);  w1.y = pack2(o[10], o[11]);
      w1.z = pack2(o[12], o[13]); w1.w = pack2(o[14], o[15]);
      hb1[(size_t)n * 2]     = w0;
      hb1[(size_t)n * 2 + 1] = w1;
    }
  }
}

// ---- aggregation: FOUR LANES PER NODE (lane q takes edges e0+q, stride 4),
//      16 f32 register accs each, shfl_xor(1,2) combine. Grid = 4x nodes. ----
template <int LAYER>
__global__ void __launch_bounds__(256)
k_aggn4(const uint2* __restrict__ payload, const int* __restrict__ rs,
        const uint4* __restrict__ hb, const float* __restrict__ dis,
        const float* __restrict__ b1, uint4* __restrict__ hb2,
        float* __restrict__ g, int N) {
  int tid = blockIdx.x * 256 + threadIdx.x;
  int n = tid >> 2;
  int q = tid & 3;
  if (n >= N) return;
  int e0 = rs[n], e1 = rs[n + 1];
  float a0 = 0, a1 = 0, a2 = 0, a3 = 0, a4 = 0, a5 = 0, a6 = 0, a7 = 0;
  float a8 = 0, a9 = 0, a10 = 0, a11 = 0, a12 = 0, a13 = 0, a14 = 0, a15 = 0;
  for (int e = e0 + q; e < e1; e += 4) {
    uint2 p = payload[e];
    const uint4* row = hb + ((size_t)p.x * 2);
    uint4 r0 = row[0];
    uint4 r1 = row[1];
    float w = __uint_as_float(p.y);
    a0  = fmaf(blo(r0.x), w, a0);  a1  = fmaf(bhi(r0.x), w, a1);
    a2  = fmaf(blo(r0.y), w, a2);  a3  = fmaf(bhi(r0.y), w, a3);
    a4  = fmaf(blo(r0.z), w, a4);  a5  = fmaf(bhi(r0.z), w, a5);
    a6  = fmaf(blo(r0.w), w, a6);  a7  = fmaf(bhi(r0.w), w, a7);
    a8  = fmaf(blo(r1.x), w, a8);  a9  = fmaf(bhi(r1.x), w, a9);
    a10 = fmaf(blo(r1.y), w, a10); a11 = fmaf(bhi(r1.y), w, a11);
    a12 = fmaf(blo(r1.z), w, a12); a13 = fmaf(bhi(r1.z), w, a13);
    a14 = fmaf(blo(r1.w), w, a14); a15 = fmaf(bhi(r1.w), w, a15);
  }
  // combine the 4 lanes of this node (xor-butterfly within 4-lane group)
#pragma unroll
  for (int m = 1; m <= 2; m <<= 1) {
    a0  += __shfl_xor(a0,  m); a1  += __shfl_xor(a1,  m);
    a2  += __shfl_xor(a2,  m); a3  += __shfl_xor(a3,  m);
    a4  += __shfl_xor(a4,  m); a5  += __shfl_xor(a5,  m);
    a6  += __shfl_xor(a6,  m); a7  += __shfl_xor(a7,  m);
    a8  += __shfl_xor(a8,  m); a9  += __shfl_xor(a9,  m);
    a10 += __shfl_xor(a10, m); a11 += __shfl_xor(a11, m);
    a12 += __shfl_xor(a12, m); a13 += __shfl_xor(a13, m);
    a14 += __shfl_xor(a14, m); a15 += __shfl_xor(a15, m);
  }
  uint4 s0 = hb[(size_t)n * 2];
  uint4 s1 = hb[(size_t)n * 2 + 1];
  float di = dis[n];
  a0  = (a0  + blo(s0.x)) * di;  a1  = (a1  + bhi(s0.x)) * di;
  a2  = (a2  + blo(s0.y)) * di;  a3  = (a3  + bhi(s0.y)) * di;
  a4  = (a4  + blo(s0.z)) * di;  a5  = (a5  + bhi(s0.z)) * di;
  a6  = (a6  + blo(s0.w)) * di;  a7  = (a7  + bhi(s0.w)) * di;
  a8  = (a8  + blo(s1.x)) * di;  a9  = (a9  + bhi(s1.x)) * di;
  a10 = (a10 + blo(s1.y)) * di;  a11 = (a11 + bhi(s1.y)) * di;
  a12 = (a12 + blo(s1.z)) * di;  a13 = (a13 + bhi(s1.z)) * di;
  a14 = (a14 + blo(s1.w)) * di;  a15 = (a15 + bhi(s1.w)) * di;
  if (LAYER == 1) {
    a0  = fmaxf(a0  + b1[0],  0.0f) * di;  a1  = fmaxf(a1  + b1[1],  0.0f) * di;
    a2  = fmaxf(a2  + b1[2],  0.0f) * di;  a3  = fmaxf(a3  + b1[3],  0.0f) * di;
    a4  = fmaxf(a4  + b1[4],  0.0f) * di;  a5  = fmaxf(a5  + b1[5],  0.0f) * di;
    a6  = fmaxf(a6  + b1[6],  0.0f) * di;  a7  = fmaxf(a7  + b1[7],  0.0f) * di;
    a8  = fmaxf(a8  + b1[8],  0.0f) * di;  a9  = fmaxf(a9  + b1[9],  0.0f) * di;
    a10 = fmaxf(a10 + b1[10], 0.0f) * di;  a11 = fmaxf(a11 + b1[11], 0.0f) * di;
    a12 = fmaxf(a12 + b1[12], 0.0f) * di;  a13 = fmaxf(a13 + b1[13], 0.0f) * di;
    a14 = fmaxf(a14 + b1[14], 0.0f) * di;  a15 = fmaxf(a15 + b1[15], 0.0f) * di;
    if (q == 0) {
      uint4 w0;
      w0.x = pack2(a0, a1);  w0.y = pack2(a2,  a3);
      w0.z = pack2(a4, a5);  w0.w = pack2(a6,  a7);
      hb2[(size_t)n * 2] = w0;
    } else if (q == 1) {
      uint4 w1;
      w1.x = pack2(a8,  a9);  w1.y = pack2(a10, a11);
      w1.z = pack2(a12, a13); w1.w = pack2(a14, a15);
      hb2[(size_t)n * 2 + 1] = w1;
    }
  } else {
    float4* gr = reinterpret_cast<float4*>(g + (size_t)n * HID);
    if (q == 0) gr[0] = make_float4(a0,  a1,  a2,  a3);
    else if (q == 1) gr[1] = make_float4(a4,  a5,  a6,  a7);
    else if (q == 2) gr[2] = make_float4(a8,  a9,  a10, a11);
    else gr[3] = make_float4(a12, a13, a14, a15);
  }
}

// ---- out = log_softmax(g @ W2 + b2), thread-per-node ----
__global__ void k_out(const float* __restrict__ g, const float* __restrict__ W2,
                      const float* __restrict__ b2, float* __restrict__ out, int N) {
  int n = blockIdx.x * blockDim.x + threadIdx.x;
  if (n >= N) return;
  float gv[HID];
#pragma unroll
  for (int j = 0; j < HID; ++j) gv[j] = g[(size_t)n * HID + j];
  float o[NCLS];
#pragma unroll
  for (int c = 0; c < NCLS; ++c) o[c] = b2[c];
#pragma unroll
  for (int j = 0; j < HID; ++j) {
    float gj = gv[j];
    const float* wr = W2 + (size_t)j * NCLS;
#pragma unroll
    for (int c = 0; c < NCLS; ++c) o[c] = fmaf(gj, wr[c], o[c]);
  }
  float m = o[0];
#pragma unroll
  for (int c = 1; c < NCLS; ++c) m = fmaxf(m, o[c]);
  float ss = 0.0f;
#pragma unroll
  for (int c = 0; c < NCLS; ++c) ss += expf(o[c] - m);
  float lse = m + logf(ss);
  float* orow = out + (size_t)n * NCLS;
#pragma unroll
  for (int c = 0; c < NCLS; ++c) orow[c] = o[c] - lse;
}

extern "C" void kernel_launch(void* const* d_in, const int* in_sizes, int n_in,
                              void* d_out, int out_size, void* d_ws, size_t ws_size,
                              hipStream_t stream) {
  const float* x  = (const float*)d_in[0];
  const int*   ei = (const int*)d_in[1];
  const float* ew = (const float*)d_in[2];
  const float* W1 = (const float*)d_in[3];
  const float* b1 = (const float*)d_in[4];
  const float* W2 = (const float*)d_in[5];
  const float* b2 = (const float*)d_in[6];
  float* out = (float*)d_out;

  const int N = in_sizes[0] / F_IN;   // 100000
  const int E = in_sizes[2];          // 3200000
  const int* src = ei;
  const int* dst = ei + E;

  const int NB   = (N + 127) >> 7;             // 782 buckets
  const int NBLK = (E + CHUNK - 1) / CHUNK;    // 782 chunks
  const long long SCT = (long long)NB * NBLK + 1;
  const int Npad = (int)((SCT + 1023) & ~1023LL);
  const int nbScan = Npad / 1024;
  const int Nr   = (NB * 128 + 256 + 255) & ~255;
  const size_t SEGSZ = (size_t)NBLK * (NB + 1) + 4;

  // ws layout (4B words): counts[Npad] | bsum[1024] | dis[Nr] | rs[Nr] |
  //   hb1[N*8] | hb2[N*8] | g[N*16] | payloadA[2E] | segs[SEGSZ] | payloadB[2E]
  int* counts = (int*)d_ws;
  int* bsum   = counts + Npad;
  float* dis  = (float*)(bsum + 1024);
  int* rs     = (int*)(dis + Nr);
  uint4* hb1  = (uint4*)(rs + Nr);
  uint4* hb2  = hb1 + (size_t)N * 2;
  float* g    = (float*)(hb2 + (size_t)N * 2);
  uint2* payloadA = (uint2*)(g + (size_t)N * HID);
  int* segs   = (int*)(payloadA + (size_t)E);
  uint2* payloadB = (uint2*)(segs + SEGSZ);

  const int padLo = NB * NBLK;
  k_zpad<<<(Npad - padLo + 255) / 256, 256, 0, stream>>>(counts, padLo, Npad);
  k_count<<<NBLK, 256, 0, stream>>>(dst, counts, E, NB, NBLK);
  k_scanA<<<nbScan, 256, 0, stream>>>(counts, bsum);
  k_scanB<<<1, 1024, 0, stream>>>(bsum, nbScan);
  k_scanC<<<nbScan, 256, 0, stream>>>(counts, bsum);
  k_scat2<<<NBLK, 256, 0, stream>>>(src, dst, ew, payloadA, segs, E, NB);
  k_sortb2<<<NB, 256, 0, stream>>>(payloadA, segs, counts, payloadB, rs, dis, N, NB, NBLK);
  k_gemm1d<<<(N + 63) / 64, 256, 0, stream>>>(x, W1, dis, hb1, N);
  const int gAgg = (N * 4 + 255) / 256;
  k_aggn4<1><<<gAgg, 256, 0, stream>>>(payloadB, rs, hb1, dis, b1, hb2, nullptr, N);
  k_aggn4<2><<<gAgg, 256, 0, stream>>>(payloadB, rs, hb2, dis, nullptr, nullptr, g, N);
  k_out<<<(N + 255) / 256, 256, 0, stream>>>(g, W2, b2, out, N);
}

// Round 14
// 252.693 us; speedup vs baseline: 1.7583x; 1.3095x over previous
//
#include <hip/hip_runtime.h>
#include <hip/hip_bf16.h>

constexpr int F_IN  = 512;
constexpr int HID   = 16;
constexpr int NCLS  = 40;
constexpr int CHUNK = 4096;   // edges per chunk
constexpr int BMAX  = 800;    // max buckets (N=100000 -> NB=782)
constexpr int SMAX  = 6144;   // max edges per bucket

// ---- zero the scan pad [lo,hi) of counts ----
__global__ void k_zpad(int* __restrict__ counts, int lo, int hi) {
  int i = lo + blockIdx.x * 256 + threadIdx.x;
  if (i < hi) counts[i] = 0;
}

// ---- Pass A: per-chunk histogram of dst buckets (LDS atomics only) ----
__global__ void k_count(const int* __restrict__ dst, int* __restrict__ counts,
                        int E, int NB, int NBLK) {
  __shared__ int hist[BMAX];
  int t = threadIdx.x;
  for (int b = t; b < BMAX; b += 256) hist[b] = 0;
  __syncthreads();
  int base = blockIdx.x * CHUNK;
  for (int i = 0; i < CHUNK; i += 256) {
    int e = base + i + t;
    if (e < E) atomicAdd(&hist[dst[e] >> 7], 1);
  }
  __syncthreads();
  for (int b = t; b < NB; b += 256) counts[b * NBLK + blockIdx.x] = hist[b];
}

// ---- scan over counts (bucket-major), 3 stages, in-place ----
__global__ void k_scanA(const int* __restrict__ a, int* __restrict__ bsum) {
  __shared__ int sd[256];
  int t = threadIdx.x;
  int4 v = reinterpret_cast<const int4*>(a)[blockIdx.x * 256 + t];
  sd[t] = v.x + v.y + v.z + v.w;
  __syncthreads();
  for (int off = 128; off > 0; off >>= 1) {
    if (t < off) sd[t] += sd[t + off];
    __syncthreads();
  }
  if (!t) bsum[blockIdx.x] = sd[0];
}

__global__ void k_scanB(int* __restrict__ bsum, int nb) {
  __shared__ int sd[1024];
  int t = threadIdx.x;
  int v = (t < nb) ? bsum[t] : 0;
  sd[t] = v;
  __syncthreads();
  for (int off = 1; off < 1024; off <<= 1) {
    int add = (t >= off) ? sd[t - off] : 0;
    __syncthreads();
    sd[t] += add;
    __syncthreads();
  }
  if (t < nb) bsum[t] = sd[t] - v;  // exclusive
}

__global__ void k_scanC(int* __restrict__ a, const int* __restrict__ bsum) {
  __shared__ int sd[256];
  int t = threadIdx.x;
  int4 v = reinterpret_cast<int4*>(a)[blockIdx.x * 256 + t];
  int ts = v.x + v.y + v.z + v.w;
  sd[t] = ts;
  __syncthreads();
  for (int off = 1; off < 256; off <<= 1) {
    int add = (t >= off) ? sd[t - off] : 0;
    __syncthreads();
    sd[t] += add;
    __syncthreads();
  }
  int pre = bsum[blockIdx.x] + sd[t] - ts;
  int4 w;
  w.x = pre; w.y = pre + v.x; w.z = w.y + v.y; w.w = w.z + v.z;
  reinterpret_cast<int4*>(a)[blockIdx.x * 256 + t] = w;
}

// ---- Pass B: chunk-local LDS counting sort by bucket; STREAMING writes ----
__global__ void __launch_bounds__(256)
k_scat2(const int* __restrict__ src, const int* __restrict__ dst,
        const float* __restrict__ ew, uint2* __restrict__ payloadA,
        int* __restrict__ segs, int E, int NB) {
  __shared__ uint2 ebuf[CHUNK];
  __shared__ int hist[1024];
  __shared__ int sc[256];
  int t = threadIdx.x;
  int c = blockIdx.x;
  int cbase = c * CHUNK;
  int sz = min(CHUNK, E - cbase);
#pragma unroll
  for (int i = 0; i < 4; ++i) hist[t + 256 * i] = 0;
  __syncthreads();
  uint2 pk[16];
  int key[16];
#pragma unroll
  for (int r = 0; r < 16; ++r) {
    int i = r * 256 + t;
    int e = cbase + i;
    if (i < sz) {
      int s = src[e], d = dst[e];
      pk[r] = make_uint2(((unsigned)s << 7) | (unsigned)(d & 127),
                         __float_as_uint(ew[e]));
      key[r] = d >> 7;
      atomicAdd(&hist[key[r]], 1);
    } else {
      key[r] = -1;
    }
  }
  __syncthreads();
  int h0 = hist[4 * t], h1 = hist[4 * t + 1], h2 = hist[4 * t + 2], h3 = hist[4 * t + 3];
  int tsum = h0 + h1 + h2 + h3;
  sc[t] = tsum;
  __syncthreads();
  for (int off = 1; off < 256; off <<= 1) {
    int add = (t >= off) ? sc[t - off] : 0;
    __syncthreads();
    sc[t] += add;
    __syncthreads();
  }
  int pre = sc[t] - tsum;
  __syncthreads();
  hist[4 * t]     = pre;
  hist[4 * t + 1] = pre + h0;
  hist[4 * t + 2] = pre + h0 + h1;
  hist[4 * t + 3] = pre + h0 + h1 + h2;
  __syncthreads();
  size_t sb = (size_t)c * (NB + 1);
  for (int b = t; b < NB; b += 256) segs[sb + b] = hist[b];
  if (t == 0) segs[sb + NB] = sz;
  __syncthreads();
#pragma unroll
  for (int r = 0; r < 16; ++r) {
    if (key[r] >= 0) {
      int pos = atomicAdd(&hist[key[r]], 1);
      ebuf[pos] = pk[r];
    }
  }
  __syncthreads();
  for (int i = t; i < sz; i += 256) payloadA[cbase + i] = ebuf[i];
}

// ---- Pass C: per-bucket assembly + node counting sort; streaming writes ----
__global__ void __launch_bounds__(256)
k_sortb2(const uint2* __restrict__ payloadA, const int* __restrict__ segs,
         const int* __restrict__ cnts, uint2* __restrict__ payloadB,
         int* __restrict__ rs, float* __restrict__ dis,
         int N, int NB, int NBLK) {
  __shared__ uint2 ebuf[SMAX];
  __shared__ int hcnt[128];
  __shared__ int scn[128];
  __shared__ float dgs[128];
  int t = threadIdx.x;
  int b = blockIdx.x;
  if (t < 128) { hcnt[t] = 0; dgs[t] = 1.0f; }
  __syncthreads();
  int beg = cnts[b * NBLK];
  int end = cnts[b * NBLK + NBLK];
  for (int c = t; c < NBLK; c += 256) {
    int rel = cnts[b * NBLK + c] - beg;
    size_t sb = (size_t)c * (NB + 1) + b;
    int s0 = segs[sb], s1 = segs[sb + 1];
    int gsrc = c * CHUNK + s0;
    for (int k = 0; k < s1 - s0; ++k) {
      uint2 p = payloadA[gsrc + k];
      ebuf[rel + k] = p;
      atomicAdd(&hcnt[p.x & 127], 1);
      atomicAdd(&dgs[p.x & 127], __uint_as_float(p.y));
    }
  }
  __syncthreads();
  int v = (t < 128) ? hcnt[t] : 0;
  if (t < 128) scn[t] = v;
  __syncthreads();
  for (int off = 1; off < 128; off <<= 1) {
    int add = (t < 128 && t >= off) ? scn[t - off] : 0;
    __syncthreads();
    if (t < 128) scn[t] += add;
    __syncthreads();
  }
  int base = b * 128;
  if (t < 128) {
    int st = scn[t] - v;
    hcnt[t] = st;
    rs[base + t] = beg + st;
    int n = base + t;
    if (n < N) dis[n] = rsqrtf(dgs[t]);
  }
  if (t == 0) rs[base + 128] = end;
  __syncthreads();
  int sz = end - beg;
  for (int i = t; i < sz; i += 256) {
    uint2 p = ebuf[i];
    int pos = beg + atomicAdd(&hcnt[p.x & 127], 1);
    payloadB[pos] = make_uint2(p.x >> 7, p.y);
  }
}

__device__ __forceinline__ float blo(unsigned u) { return __uint_as_float(u << 16); }
__device__ __forceinline__ float bhi(unsigned u) { return __uint_as_float(u & 0xffff0000u); }
__device__ __forceinline__ unsigned pack2(float lo, float hi) {
  __hip_bfloat16 l = __float2bfloat16(lo), h = __float2bfloat16(hi);
  unsigned short ul = *reinterpret_cast<unsigned short*>(&l);
  unsigned short uh = *reinterpret_cast<unsigned short*>(&h);
  return (unsigned)ul | ((unsigned)uh << 16);
}

// ---- h1' = (x @ W1) * dis : LDS-staged, double-buffered, scalar W1.
//      Tile = 64 rows; 4 K-chunks of 128. Staging = lane-linear coalesced
//      float4 -> bf16-packed LDS [64][65 u32]. Compute: lane = row (2-way
//      LDS alias, free), k wave-uniform -> W1 via s_load. 1 barrier/chunk. ----
__global__ void __launch_bounds__(256)
k_gemm1e(const float* __restrict__ x, const float* __restrict__ W1,
         const float* __restrict__ dis, uint4* __restrict__ hb1, int N) {
  __shared__ unsigned xs[2 * 64 * 65];   // 33.3 KB total; epilogue overlays
  int t = threadIdx.x;
  int nb = blockIdx.x * 64;
  int r = t & 63;
  int sId = __builtin_amdgcn_readfirstlane(t >> 6);   // wave id 0..3, scalar
  float2 acc[8];
#pragma unroll
  for (int j2 = 0; j2 < 8; ++j2) acc[j2] = make_float2(0.f, 0.f);

  float4 ld0, ld1, ld2, ld3, ld4, ld5, ld6, ld7;
  // LOAD(c): 8 lane-linear float4 (512B segments), rows guarded
#define G1E_LOAD(c)                                                          \
  do {                                                                       \
    int f;                                                                   \
    f = t;           { int row = f >> 5, sl = f & 31; int n = nb + row;      \
      ld0 = (n < N) ? *reinterpret_cast<const float4*>(x + (size_t)n * F_IN + (c) * 128 + sl * 4) : make_float4(0,0,0,0); } \
    f = t + 256;     { int row = f >> 5, sl = f & 31; int n = nb + row;      \
      ld1 = (n < N) ? *reinterpret_cast<const float4*>(x + (size_t)n * F_IN + (c) * 128 + sl * 4) : make_float4(0,0,0,0); } \
    f = t + 512;     { int row = f >> 5, sl = f & 31; int n = nb + row;      \
      ld2 = (n < N) ? *reinterpret_cast<const float4*>(x + (size_t)n * F_IN + (c) * 128 + sl * 4) : make_float4(0,0,0,0); } \
    f = t + 768;     { int row = f >> 5, sl = f & 31; int n = nb + row;      \
      ld3 = (n < N) ? *reinterpret_cast<const float4*>(x + (size_t)n * F_IN + (c) * 128 + sl * 4) : make_float4(0,0,0,0); } \
    f = t + 1024;    { int row = f >> 5, sl = f & 31; int n = nb + row;      \
      ld4 = (n < N) ? *reinterpret_cast<const float4*>(x + (size_t)n * F_IN + (c) * 128 + sl * 4) : make_float4(0,0,0,0); } \
    f = t + 1280;    { int row = f >> 5, sl = f & 31; int n = nb + row;      \
      ld5 = (n < N) ? *reinterpret_cast<const float4*>(x + (size_t)n * F_IN + (c) * 128 + sl * 4) : make_float4(0,0,0,0); } \
    f = t + 1536;    { int row = f >> 5, sl = f & 31; int n = nb + row;      \
      ld6 = (n < N) ? *reinterpret_cast<const float4*>(x + (size_t)n * F_IN + (c) * 128 + sl * 4) : make_float4(0,0,0,0); } \
    f = t + 1792;    { int row = f >> 5, sl = f & 31; int n = nb + row;      \
      ld7 = (n < N) ? *reinterpret_cast<const float4*>(x + (size_t)n * F_IN + (c) * 128 + sl * 4) : make_float4(0,0,0,0); } \
  } while (0)
#define G1E_STORE(buf)                                                       \
  do {                                                                       \
    unsigned* bp = &xs[(buf) * 4160];                                        \
    int f;                                                                   \
    f = t;        { int row = f >> 5, sl = f & 31; int w = row * 65 + sl * 2; \
      bp[w] = pack2(ld0.x, ld0.y); bp[w + 1] = pack2(ld0.z, ld0.w); }        \
    f = t + 256;  { int row = f >> 5, sl = f & 31; int w = row * 65 + sl * 2; \
      bp[w] = pack2(ld1.x, ld1.y); bp[w + 1] = pack2(ld1.z, ld1.w); }        \
    f = t + 512;  { int row = f >> 5, sl = f & 31; int w = row * 65 + sl * 2; \
      bp[w] = pack2(ld2.x, ld2.y); bp[w + 1] = pack2(ld2.z, ld2.w); }        \
    f = t + 768;  { int row = f >> 5, sl = f & 31; int w = row * 65 + sl * 2; \
      bp[w] = pack2(ld3.x, ld3.y); bp[w + 1] = pack2(ld3.z, ld3.w); }        \
    f = t + 1024; { int row = f >> 5, sl = f & 31; int w = row * 65 + sl * 2; \
      bp[w] = pack2(ld4.x, ld4.y); bp[w + 1] = pack2(ld4.z, ld4.w); }        \
    f = t + 1280; { int row = f >> 5, sl = f & 31; int w = row * 65 + sl * 2; \
      bp[w] = pack2(ld5.x, ld5.y); bp[w + 1] = pack2(ld5.z, ld5.w); }        \
    f = t + 1536; { int row = f >> 5, sl = f & 31; int w = row * 65 + sl * 2; \
      bp[w] = pack2(ld6.x, ld6.y); bp[w + 1] = pack2(ld6.z, ld6.w); }        \
    f = t + 1792; { int row = f >> 5, sl = f & 31; int w = row * 65 + sl * 2; \
      bp[w] = pack2(ld7.x, ld7.y); bp[w + 1] = pack2(ld7.z, ld7.w); }        \
  } while (0)

  G1E_LOAD(0);
  G1E_STORE(0);
  __syncthreads();

#pragma unroll
  for (int c = 0; c < 4; ++c) {
    if (c < 3) G1E_LOAD(c + 1);
    // compute chunk c from buf c&1; k = c*128 + 2*(sId*16+mm) (+1), wave-uniform
    {
      const unsigned* xcol = &xs[(c & 1) * 4160 + r * 65 + sId * 16];
      const float* wbase = W1 + (size_t)(c * 128 + sId * 32) * HID;
#pragma unroll
      for (int mm = 0; mm < 16; ++mm) {
        unsigned u = xcol[mm];
        float x0 = blo(u), x1 = bhi(u);
        const float* w0 = wbase + mm * 32;
        const float* w1 = w0 + HID;
#pragma unroll
        for (int j2 = 0; j2 < 8; ++j2) {
          float2 p0 = *reinterpret_cast<const float2*>(w0 + 2 * j2);
          float2 p1 = *reinterpret_cast<const float2*>(w1 + 2 * j2);
          acc[j2].x = fmaf(x1, p1.x, fmaf(x0, p0.x, acc[j2].x));
          acc[j2].y = fmaf(x1, p1.y, fmaf(x0, p0.y, acc[j2].y));
        }
      }
    }
    if (c < 3) G1E_STORE((c + 1) & 1);
    __syncthreads();
  }

  // epilogue: combine 4 k-slices via stride-17 overlay (conflict-free)
  float* ps = reinterpret_cast<float*>(xs);
#pragma unroll
  for (int j2 = 0; j2 < 8; ++j2) {
    ps[(sId * 64 + r) * 17 + 2 * j2]     = acc[j2].x;
    ps[(sId * 64 + r) * 17 + 2 * j2 + 1] = acc[j2].y;
  }
  __syncthreads();
  if (t < 64) {
    int n = nb + t;
    if (n < N) {
      float di = dis[n];
      float o[HID];
#pragma unroll
      for (int j = 0; j < HID; ++j)
        o[j] = (ps[t * 17 + j] + ps[(64 + t) * 17 + j] +
                ps[(128 + t) * 17 + j] + ps[(192 + t) * 17 + j]) * di;
      uint4 w0, w1;
      w0.x = pack2(o[0],  o[1]);  w0.y = pack2(o[2],  o[3]);
      w0.z = pack2(o[4],  o[5]);  w0.w = pack2(o[6],  o[7]);
      w1.x = pack2(o[8],  o[9]);  w1.y = pack2(o[10], o[11]);
      w1.z = pack2(o[12], o[13]); w1.w = pack2(o[14], o[15]);
      hb1[(size_t)n * 2]     = w0;
      hb1[(size_t)n * 2 + 1] = w1;
    }
  }
#undef G1E_LOAD
#undef G1E_STORE
}

// ---- aggregation: FOUR LANES PER NODE, 16 f32 register accs, shfl combine ----
template <int LAYER>
__global__ void __launch_bounds__(256)
k_aggn4(const uint2* __restrict__ payload, const int* __restrict__ rs,
        const uint4* __restrict__ hb, const float* __restrict__ dis,
        const float* __restrict__ b1, uint4* __restrict__ hb2,
        float* __restrict__ g, int N) {
  int tid = blockIdx.x * 256 + threadIdx.x;
  int n = tid >> 2;
  int q = tid & 3;
  if (n >= N) return;
  int e0 = rs[n], e1 = rs[n + 1];
  float a0 = 0, a1 = 0, a2 = 0, a3 = 0, a4 = 0, a5 = 0, a6 = 0, a7 = 0;
  float a8 = 0, a9 = 0, a10 = 0, a11 = 0, a12 = 0, a13 = 0, a14 = 0, a15 = 0;
  for (int e = e0 + q; e < e1; e += 4) {
    uint2 p = payload[e];
    const uint4* row = hb + ((size_t)p.x * 2);
    uint4 r0 = row[0];
    uint4 r1 = row[1];
    float w = __uint_as_float(p.y);
    a0  = fmaf(blo(r0.x), w, a0);  a1  = fmaf(bhi(r0.x), w, a1);
    a2  = fmaf(blo(r0.y), w, a2);  a3  = fmaf(bhi(r0.y), w, a3);
    a4  = fmaf(blo(r0.z), w, a4);  a5  = fmaf(bhi(r0.z), w, a5);
    a6  = fmaf(blo(r0.w), w, a6);  a7  = fmaf(bhi(r0.w), w, a7);
    a8  = fmaf(blo(r1.x), w, a8);  a9  = fmaf(bhi(r1.x), w, a9);
    a10 = fmaf(blo(r1.y), w, a10); a11 = fmaf(bhi(r1.y), w, a11);
    a12 = fmaf(blo(r1.z), w, a12); a13 = fmaf(bhi(r1.z), w, a13);
    a14 = fmaf(blo(r1.w), w, a14); a15 = fmaf(bhi(r1.w), w, a15);
  }
#pragma unroll
  for (int m = 1; m <= 2; m <<= 1) {
    a0  += __shfl_xor(a0,  m); a1  += __shfl_xor(a1,  m);
    a2  += __shfl_xor(a2,  m); a3  += __shfl_xor(a3,  m);
    a4  += __shfl_xor(a4,  m); a5  += __shfl_xor(a5,  m);
    a6  += __shfl_xor(a6,  m); a7  += __shfl_xor(a7,  m);
    a8  += __shfl_xor(a8,  m); a9  += __shfl_xor(a9,  m);
    a10 += __shfl_xor(a10, m); a11 += __shfl_xor(a11, m);
    a12 += __shfl_xor(a12, m); a13 += __shfl_xor(a13, m);
    a14 += __shfl_xor(a14, m); a15 += __shfl_xor(a15, m);
  }
  uint4 s0 = hb[(size_t)n * 2];
  uint4 s1 = hb[(size_t)n * 2 + 1];
  float di = dis[n];
  a0  = (a0  + blo(s0.x)) * di;  a1  = (a1  + bhi(s0.x)) * di;
  a2  = (a2  + blo(s0.y)) * di;  a3  = (a3  + bhi(s0.y)) * di;
  a4  = (a4  + blo(s0.z)) * di;  a5  = (a5  + bhi(s0.z)) * di;
  a6  = (a6  + blo(s0.w)) * di;  a7  = (a7  + bhi(s0.w)) * di;
  a8  = (a8  + blo(s1.x)) * di;  a9  = (a9  + bhi(s1.x)) * di;
  a10 = (a10 + blo(s1.y)) * di;  a11 = (a11 + bhi(s1.y)) * di;
  a12 = (a12 + blo(s1.z)) * di;  a13 = (a13 + bhi(s1.z)) * di;
  a14 = (a14 + blo(s1.w)) * di;  a15 = (a15 + bhi(s1.w)) * di;
  if (LAYER == 1) {
    a0  = fmaxf(a0  + b1[0],  0.0f) * di;  a1  = fmaxf(a1  + b1[1],  0.0f) * di;
    a2  = fmaxf(a2  + b1[2],  0.0f) * di;  a3  = fmaxf(a3  + b1[3],  0.0f) * di;
    a4  = fmaxf(a4  + b1[4],  0.0f) * di;  a5  = fmaxf(a5  + b1[5],  0.0f) * di;
    a6  = fmaxf(a6  + b1[6],  0.0f) * di;  a7  = fmaxf(a7  + b1[7],  0.0f) * di;
    a8  = fmaxf(a8  + b1[8],  0.0f) * di;  a9  = fmaxf(a9  + b1[9],  0.0f) * di;
    a10 = fmaxf(a10 + b1[10], 0.0f) * di;  a11 = fmaxf(a11 + b1[11], 0.0f) * di;
    a12 = fmaxf(a12 + b1[12], 0.0f) * di;  a13 = fmaxf(a13 + b1[13], 0.0f) * di;
    a14 = fmaxf(a14 + b1[14], 0.0f) * di;  a15 = fmaxf(a15 + b1[15], 0.0f) * di;
    if (q == 0) {
      uint4 w0;
      w0.x = pack2(a0, a1);  w0.y = pack2(a2,  a3);
      w0.z = pack2(a4, a5);  w0.w = pack2(a6,  a7);
      hb2[(size_t)n * 2] = w0;
    } else if (q == 1) {
      uint4 w1;
      w1.x = pack2(a8,  a9);  w1.y = pack2(a10, a11);
      w1.z = pack2(a12, a13); w1.w = pack2(a14, a15);
      hb2[(size_t)n * 2 + 1] = w1;
    }
  } else {
    float4* gr = reinterpret_cast<float4*>(g + (size_t)n * HID);
    if (q == 0) gr[0] = make_float4(a0,  a1,  a2,  a3);
    else if (q == 1) gr[1] = make_float4(a4,  a5,  a6,  a7);
    else if (q == 2) gr[2] = make_float4(a8,  a9,  a10, a11);
    else gr[3] = make_float4(a12, a13, a14, a15);
  }
}

// ---- out = log_softmax(g @ W2 + b2), thread-per-node ----
__global__ void k_out(const float* __restrict__ g, const float* __restrict__ W2,
                      const float* __restrict__ b2, float* __restrict__ out, int N) {
  int n = blockIdx.x * blockDim.x + threadIdx.x;
  if (n >= N) return;
  float gv[HID];
#pragma unroll
  for (int j = 0; j < HID; ++j) gv[j] = g[(size_t)n * HID + j];
  float o[NCLS];
#pragma unroll
  for (int c = 0; c < NCLS; ++c) o[c] = b2[c];
#pragma unroll
  for (int j = 0; j < HID; ++j) {
    float gj = gv[j];
    const float* wr = W2 + (size_t)j * NCLS;
#pragma unroll
    for (int c = 0; c < NCLS; ++c) o[c] = fmaf(gj, wr[c], o[c]);
  }
  float m = o[0];
#pragma unroll
  for (int c = 1; c < NCLS; ++c) m = fmaxf(m, o[c]);
  float ss = 0.0f;
#pragma unroll
  for (int c = 0; c < NCLS; ++c) ss += expf(o[c] - m);
  float lse = m + logf(ss);
  float* orow = out + (size_t)n * NCLS;
#pragma unroll
  for (int c = 0; c < NCLS; ++c) orow[c] = o[c] - lse;
}

extern "C" void kernel_launch(void* const* d_in, const int* in_sizes, int n_in,
                              void* d_out, int out_size, void* d_ws, size_t ws_size,
                              hipStream_t stream) {
  const float* x  = (const float*)d_in[0];
  const int*   ei = (const int*)d_in[1];
  const float* ew = (const float*)d_in[2];
  const float* W1 = (const float*)d_in[3];
  const float* b1 = (const float*)d_in[4];
  const float* W2 = (const float*)d_in[5];
  const float* b2 = (const float*)d_in[6];
  float* out = (float*)d_out;

  const int N = in_sizes[0] / F_IN;   // 100000
  const int E = in_sizes[2];          // 3200000
  const int* src = ei;
  const int* dst = ei + E;

  const int NB   = (N + 127) >> 7;             // 782 buckets
  const int NBLK = (E + CHUNK - 1) / CHUNK;    // 782 chunks
  const long long SCT = (long long)NB * NBLK + 1;
  const int Npad = (int)((SCT + 1023) & ~1023LL);
  const int nbScan = Npad / 1024;
  const int Nr   = (NB * 128 + 256 + 255) & ~255;
  const size_t SEGSZ = (size_t)NBLK * (NB + 1) + 4;

  // ws layout (4B words): counts[Npad] | bsum[1024] | dis[Nr] | rs[Nr] |
  //   hb1[N*8] | hb2[N*8] | g[N*16] | payloadA[2E] | segs[SEGSZ] | payloadB[2E]
  int* counts = (int*)d_ws;
  int* bsum   = counts + Npad;
  float* dis  = (float*)(bsum + 1024);
  int* rs     = (int*)(dis + Nr);
  uint4* hb1  = (uint4*)(rs + Nr);
  uint4* hb2  = hb1 + (size_t)N * 2;
  float* g    = (float*)(hb2 + (size_t)N * 2);
  uint2* payloadA = (uint2*)(g + (size_t)N * HID);
  int* segs   = (int*)(payloadA + (size_t)E);
  uint2* payloadB = (uint2*)(segs + SEGSZ);

  const int padLo = NB * NBLK;
  k_zpad<<<(Npad - padLo + 255) / 256, 256, 0, stream>>>(counts, padLo, Npad);
  k_count<<<NBLK, 256, 0, stream>>>(dst, counts, E, NB, NBLK);
  k_scanA<<<nbScan, 256, 0, stream>>>(counts, bsum);
  k_scanB<<<1, 1024, 0, stream>>>(bsum, nbScan);
  k_scanC<<<nbScan, 256, 0, stream>>>(counts, bsum);
  k_scat2<<<NBLK, 256, 0, stream>>>(src, dst, ew, payloadA, segs, E, NB);
  k_sortb2<<<NB, 256, 0, stream>>>(payloadA, segs, counts, payloadB, rs, dis, N, NB, NBLK);
  k_gemm1e<<<(N + 63) / 64, 256, 0, stream>>>(x, W1, dis, hb1, N);
  const int gAgg = (N * 4 + 255) / 256;
  k_aggn4<1><<<gAgg, 256, 0, stream>>>(payloadB, rs, hb1, dis, b1, hb2, nullptr, N);
  k_aggn4<2><<<gAgg, 256, 0, stream>>>(payloadB, rs, hb2, dis, nullptr, nullptr, g, N);
  k_out<<<(N + 255) / 256, 256, 0, stream>>>(g, W2, b2, out, N);
}